// Round 1
// baseline (8076.264 us; speedup 1.0000x reference)
//
#include <hip/hip_runtime.h>
#include <hip/hip_bf16.h>
#include <stdint.h>

// Problem constants (fixed by setup_inputs): B=8, S=200, H=256, V=32000, T=51
// outputs: (8, 50, 64000) fp32 + scalar loss  -> out_size = 25,600,001

#define DEVI __device__ __forceinline__

// ---------------- ws layout (float offsets). Total ~27 MB. ----------------
static constexpr size_t OFF_COV   = 0;                       // 1600 (zeroed)
static constexpr size_t OFF_ACC   = 1600;                    // 4: nll_sum, valid_sum, bce_sum, m_sum (zeroed)
static constexpr size_t OFF_BAR   = 1604;                    // 12 ints: enc dir0 cnt/gen, enc dir1 cnt/gen, dec cnt/gen (zeroed)
static constexpr size_t ZERO_FLOATS = 1616;
static constexpr size_t OFF_EMB   = 2048;                    // [t][b][h] 200*8*256
static constexpr size_t OFF_EMBR  = OFF_EMB  + 409600;       // reversed-t emb
static constexpr size_t OFF_PREF  = OFF_EMBR + 409600;       // [t][b][j] 200*8*1024
static constexpr size_t OFF_PREB  = OFF_PREF + 1638400;
static constexpr size_t OFF_BIAS  = OFF_PREB + 1638400;      // 3*1024 summed biases (f,b,d)
static constexpr size_t OFF_HB    = OFF_BIAS + 3072;         // enc h dbl-buf [dir][par][b][256] = 8192
static constexpr size_t OFF_HFIN  = OFF_HB   + 8192;         // [dir][b][256] = 4096
static constexpr size_t OFF_CFIN  = OFF_HFIN + 4096;         // 4096
static constexpr size_t OFF_ENCOUT= OFF_CFIN + 4096;         // [b][s][512] = 819200
static constexpr size_t OFF_HSEL  = OFF_ENCOUT + 819200;     // [b*200+s][256] = 409600
static constexpr size_t OFF_CP    = OFF_HSEL + 409600;       // 1600
static constexpr size_t OFF_MASK  = OFF_CP   + 1600;         // 1600 (float 0/1)
static constexpr size_t OFF_H0    = OFF_MASK + 1600;         // 2048
static constexpr size_t OFF_C0    = OFF_H0   + 2048;         // 2048
static constexpr size_t OFF_EP    = OFF_C0   + 2048;         // [b][s][256] = 409600
static constexpr size_t OFF_WCP   = OFF_EP   + 409600;       // 256
static constexpr size_t OFF_BCP   = OFF_WCP  + 256;          // 256
static constexpr size_t OFF_DEMB  = OFF_BCP  + 256;          // [t][b][h] 50*8*256 = 102400
static constexpr size_t OFF_DPRE  = OFF_DEMB + 102400;       // [t][b][j] 50*8*1024 = 409600
static constexpr size_t OFF_HBUF  = OFF_DPRE + 409600;       // dec h state [b][256] = 2048
static constexpr size_t OFF_HCAT  = OFF_HBUF + 2048;         // [b][768] = 6144
static constexpr size_t OFF_SC    = OFF_HCAT + 6144;         // scores [b][200] = 1600
static constexpr size_t OFF_CS    = OFF_SC   + 1600;         // ctx store [t][b][512] = 204800
static constexpr size_t OFF_HS    = OFF_CS   + 204800;       // h store [t][b][256] = 102400
static constexpr size_t OFF_AS    = OFF_HS   + 102400;       // attn store [t][b][200] = 80000
static constexpr size_t OFF_PG    = OFF_AS   + 80000;        // 400
static constexpr size_t OFF_HWP   = OFF_PG   + 408;          // hW partials [g=32][b=8][256] = 65536

// ---------------- helpers ----------------
DEVI float sigf(float x)       { return 1.0f / (1.0f + __expf(-x)); }
DEVI float tanh_fast(float x)  { return 1.0f - 2.0f / (1.0f + __expf(2.0f * x)); }
DEVI float pick4(float z, float x1, float x2, float x3, int mm) {
  return mm == 0 ? z : (mm == 1 ? x1 : (mm == 2 ? x2 : x3));
}

// Device-scope arrive/release barrier among `n` co-resident blocks.
DEVI void grid_barrier(int* cnt, int* gen, int n) {
  __syncthreads();
  if (threadIdx.x == 0) {
    int g = __hip_atomic_load(gen, __ATOMIC_RELAXED, __HIP_MEMORY_SCOPE_AGENT);
    int c = __hip_atomic_fetch_add(cnt, 1, __ATOMIC_ACQ_REL, __HIP_MEMORY_SCOPE_AGENT);
    if (c == n - 1) {
      __hip_atomic_store(cnt, 0, __ATOMIC_RELAXED, __HIP_MEMORY_SCOPE_AGENT);
      __hip_atomic_store(gen, g + 1, __ATOMIC_RELEASE, __HIP_MEMORY_SCOPE_AGENT);
    } else {
      while (__hip_atomic_load(gen, __ATOMIC_ACQUIRE, __HIP_MEMORY_SCOPE_AGENT) == g)
        __builtin_amdgcn_s_sleep(2);
    }
  }
  __syncthreads();
}

// ---------------- small prep kernels ----------------
__global__ __launch_bounds__(256) void k_biassum(
    const float* bih_f, const float* bhh_f, const float* bih_b, const float* bhh_b,
    const float* bih_d, const float* bhh_d, float* ws) {
  int i = blockIdx.x * 256 + threadIdx.x;     // 3072
  int which = i >> 10, jj = i & 1023;
  float v = (which == 0) ? bih_f[jj] + bhh_f[jj]
          : (which == 1) ? bih_b[jj] + bhh_b[jj]
                         : bih_d[jj] + bhh_d[jj];
  ws[OFF_BIAS + i] = v;
}

__global__ __launch_bounds__(256) void k_embed(
    const int* xin, const int* labels, const float* emb_enc, const float* emb_dec, float* ws) {
  int r = blockIdx.x, h = threadIdx.x;
  if (r < 1600) {
    int t = r >> 3, b = r & 7;
    float v = emb_enc[(size_t)xin[b * 200 + t] * 256 + h];
    ws[OFF_EMB  + (size_t)r * 256 + h] = v;
    ws[OFF_EMBR + ((size_t)(199 - t) * 8 + b) * 256 + h] = v;
  } else {
    int r2 = r - 1600;
    int t = r2 >> 3, b = r2 & 7;
    int tok = (t == 0) ? 1 : labels[b * 51 + t];     // dec_in: BOS then labels[:,1:50]
    ws[OFF_DEMB + (size_t)r2 * 256 + h] = emb_dec[(size_t)tok * 256 + h];
  }
}

// ---------------- generic tiled SGEMM: C[m][n] = act(sum_k A[m][k]*B[n][k] + bias[n]) ----------------
template<int BM, int BN, int TM, int TN, int CMAP, int ACT>
__global__ __launch_bounds__(256) void k_gemm(
    const float* __restrict__ A, const float* __restrict__ B,
    const float* __restrict__ bias, float* __restrict__ C,
    int M, int K, int ldb, int ldc) {
  __shared__ float As[16][BM];
  __shared__ float Bs[16][BN];
  const int tid = threadIdx.x;
  const int tx = tid & 15, ty = tid >> 4;
  const int m0 = blockIdx.x * BM, n0 = blockIdx.y * BN;
  float acc[TM][TN];
#pragma unroll
  for (int i = 0; i < TM; ++i)
#pragma unroll
    for (int q = 0; q < TN; ++q) acc[i][q] = 0.f;

  for (int kk = 0; kk < K; kk += 16) {
#pragma unroll
    for (int e = tid; e < BM * 4; e += 256) {
      int m = e >> 2, k4 = (e & 3) * 4;
      int gm = m0 + m;
      float4 v = {0.f, 0.f, 0.f, 0.f};
      if (gm < M) v = *(const float4*)(A + (size_t)gm * K + kk + k4);
      As[k4 + 0][m] = v.x; As[k4 + 1][m] = v.y; As[k4 + 2][m] = v.z; As[k4 + 3][m] = v.w;
    }
#pragma unroll
    for (int e = tid; e < BN * 4; e += 256) {
      int n = e >> 2, k4 = (e & 3) * 4;
      float4 v = *(const float4*)(B + (size_t)(n0 + n) * ldb + kk + k4);
      Bs[k4 + 0][n] = v.x; Bs[k4 + 1][n] = v.y; Bs[k4 + 2][n] = v.z; Bs[k4 + 3][n] = v.w;
    }
    __syncthreads();
#pragma unroll
    for (int k = 0; k < 16; ++k) {
      float a[TM], bv[TN];
#pragma unroll
      for (int i = 0; i < TM; ++i) a[i] = As[k][ty * TM + i];
#pragma unroll
      for (int q = 0; q < TN; ++q) bv[q] = Bs[k][tx * TN + q];
#pragma unroll
      for (int i = 0; i < TM; ++i)
#pragma unroll
        for (int q = 0; q < TN; ++q) acc[i][q] += a[i] * bv[q];
    }
    __syncthreads();
  }
#pragma unroll
  for (int i = 0; i < TM; ++i) {
    int gm = m0 + ty * TM + i;
    if (gm >= M) continue;
    size_t base;
    if (CMAP == 1) { int t = gm >> 3, b = gm & 7; base = (size_t)(b * 50 + t) * 64000; }
    else            base = (size_t)gm * ldc;
#pragma unroll
    for (int q = 0; q < TN; ++q) {
      int n = n0 + tx * TN + q;
      float v = acc[i][q] + bias[n];
      if (ACT == 1) v = tanh_fast(v);
      C[base + n] = v;
    }
  }
}

// ---------------- encoder: 32 blocks (16 per direction), 1 barrier/step ----------------
__global__ __launch_bounds__(512, 1) void k_encoder(
    const float* __restrict__ whh_f, const float* __restrict__ whh_b, float* __restrict__ ws) {
  const int dir = blockIdx.x & 1;
  const int ubase = (blockIdx.x >> 1) * 16;   // 16 units per block
  const float* whh = dir ? whh_b : whh_f;
  const float* pre = ws + (dir ? OFF_PREB : OFF_PREF);
  float* hb  = ws + OFF_HB;
  float* enc = ws + OFF_ENCOUT;
  int* bar = (int*)(ws + OFF_BAR) + dir * 2;
  const int b = threadIdx.x >> 6;             // wave id = batch
  const int lane = threadIdx.x & 63;
  const int u_l = lane >> 2, gate = lane & 3; // quad = 4 gates of one unit
  const int u = ubase + u_l;
  const int j = gate * 256 + u;               // i,f,g,o row order of W
  const float* wrow = whh + (size_t)j * 256;
  const int bu = __builtin_amdgcn_readfirstlane(b);
  float c_reg = 0.f;

  for (int t = 0; t < 200; ++t) {
    float acc = 0.f;
    if (t > 0) {
      const float* hrow = hb + ((size_t)(dir * 2 + ((t - 1) & 1)) * 8 + bu) * 256;
#pragma unroll 8
      for (int kk = 0; kk < 256; kk += 4) {
        float4 w = *(const float4*)(wrow + kk);
        float4 h = *(const float4*)(hrow + kk);
        acc += w.x * h.x + w.y * h.y + w.z * h.z + w.w * h.w;
      }
    }
    float z = pre[((size_t)t * 8 + b) * 1024 + j] + acc;
    float x1 = __shfl_xor(z, 1);
    float x2 = __shfl_xor(z, 2);
    float x3 = __shfl_xor(z, 3);
    float zi = pick4(z, x1, x2, x3, gate);
    float zf = pick4(z, x1, x2, x3, gate ^ 1);
    float zg = pick4(z, x1, x2, x3, gate ^ 2);
    float zo = pick4(z, x1, x2, x3, gate ^ 3);
    float cn = sigf(zf) * c_reg + sigf(zi) * tanh_fast(zg);
    float hn = sigf(zo) * tanh_fast(cn);
    c_reg = cn;
    if (gate == 0) {
      hb[((size_t)(dir * 2 + (t & 1)) * 8 + b) * 256 + u] = hn;
      if (dir == 0) enc[((size_t)b * 200 + t) * 512 + u] = hn;
      else          enc[((size_t)b * 200 + (199 - t)) * 512 + 256 + u] = hn;
      if (t == 199) {
        ws[OFF_HFIN + (size_t)(dir * 8 + b) * 256 + u] = hn;
        ws[OFF_CFIN + (size_t)(dir * 8 + b) * 256 + u] = cn;
      }
    }
    grid_barrier(bar, bar + 1, 16);
  }
}

// ---------------- copy-prob head + BCE loss terms ----------------
__global__ __launch_bounds__(64) void k_selbce(
    const float* w_sel2, const float* b_sel2, const int* xin, float* ws) {
  int r = blockIdx.x, lane = threadIdx.x;
  float p = 0.f;
#pragma unroll
  for (int i = 0; i < 4; ++i) {
    int k = lane + 64 * i;
    p += ws[OFF_HSEL + (size_t)r * 256 + k] * w_sel2[k];
  }
#pragma unroll
  for (int m = 1; m < 64; m <<= 1) p += __shfl_xor(p, m);
  if (lane == 0) {
    float cp = sigf(p + b_sel2[0]);
    ws[OFF_CP + r] = cp;
    ws[OFF_MASK + r] = (cp > 1e-8f) ? 1.f : 0.f;
    int b = r / 200, s = r % 200;
    float m = (xin[b * 200 + s] != 0) ? 1.f : 0.f;
    if (m > 0.f) {
      float lp = fmaxf(logf(cp), -100.f);
      atomicAdd(ws + OFF_ACC + 2, -lp);
    }
    atomicAdd(ws + OFF_ACC + 3, m);
  }
}

// wc_proj/bc_proj: coverage feature folded through w_attn cols [768,1024)
__global__ __launch_bounds__(256) void k_wcp(
    const float* w_attn, const float* w_cov, const float* b_cov, float* ws) {
  int jj = threadIdx.x;
  float a = 0.f, c = 0.f;
  for (int h = 0; h < 256; ++h) {
    float w = w_attn[(size_t)jj * 1024 + 768 + h];
    a += w * w_cov[h];
    c += w * b_cov[h];
  }
  ws[OFF_WCP + jj] = a;
  ws[OFF_BCP + jj] = c;
}

__global__ __launch_bounds__(256) void k_h0c0(
    const float* w_rh, const float* b_rh, const float* w_rc, const float* b_rc, float* ws) {
  int b = blockIdx.x, jj = threadIdx.x;
  const float* hf  = ws + OFF_HFIN + (size_t)b * 256;
  const float* hbk = ws + OFF_HFIN + 2048 + (size_t)b * 256;
  const float* cf  = ws + OFF_CFIN + (size_t)b * 256;
  const float* cbk = ws + OFF_CFIN + 2048 + (size_t)b * 256;
  float ah = b_rh[jj], ac = b_rc[jj];
  for (int k = 0; k < 256; ++k) {
    ah += hf[k] * w_rh[(size_t)jj * 512 + k];
    ac += cf[k] * w_rc[(size_t)jj * 512 + k];
  }
  for (int k = 0; k < 256; ++k) {
    ah += hbk[k] * w_rh[(size_t)jj * 512 + 256 + k];
    ac += cbk[k] * w_rc[(size_t)jj * 512 + 256 + k];
  }
  float h0 = fmaxf(ah, 0.f), c0 = fmaxf(ac, 0.f);
  ws[OFF_H0   + (size_t)b * 256 + jj] = h0;
  ws[OFF_C0   + (size_t)b * 256 + jj] = c0;
  ws[OFF_HBUF + (size_t)b * 256 + jj] = h0;
}

// ---------------- decoder: 32 blocks, 3 phases (3 barriers) per step ----------------
__global__ __launch_bounds__(512, 1) void k_decoder(
    const float* __restrict__ wih_d, const float* __restrict__ whh_d,
    const float* __restrict__ w_attn, const float* __restrict__ w_attn_v,
    float* __restrict__ ws) {
  __shared__ float ep_s[50 * 256];   // this block's precomputed enc-part slice
  __shared__ float hw_s[256];
  __shared__ float sc_s[256];
  __shared__ float at_s[256];
  __shared__ float red_s[256];
  __shared__ float ctxp[4][512];
  __shared__ float h_s[64];
  const int g = blockIdx.x;
  const int tid = threadIdx.x;
  int* bar = (int*)(ws + OFF_BAR) + 4;
  // P1 role: (b1, s-quarter)
  const int b1 = g >> 2, sq = g & 3, s0 = sq * 50;
  // P3 role: wave = batch, lane = (u_l, gate, kc)
  const int b3 = tid >> 6;
  const int lane = tid & 63;
  const int kc = lane & 1, gate = (lane >> 1) & 3, u_l = lane >> 3;
  const int u = g * 8 + u_l;
  const int j = gate * 256 + u;
  const int bu = __builtin_amdgcn_readfirstlane(b3);
  float* cov    = ws + OFF_COV;
  float* hbuf   = ws + OFF_HBUF;
  float* hcat   = ws + OFF_HCAT;
  float* scores = ws + OFF_SC;

  for (int e = tid; e < 50 * 256; e += 512) {
    int ss = e >> 8, jj = e & 255;
    ep_s[e] = ws[OFF_EP + ((size_t)b1 * 200 + s0 + ss) * 256 + jj];
  }
  const int w1 = tid >> 6;
  const int jb4 = lane * 4;
  float4 wcp4 = *(const float4*)(ws + OFF_WCP + jb4);
  float4 bcp4 = *(const float4*)(ws + OFF_BCP + jb4);
  float4 wav4 = *(const float4*)(w_attn_v + jb4);
  float c_reg = ws[OFF_C0 + (size_t)b3 * 256 + u];
  __syncthreads();

  for (int t = 0; t < 50; ++t) {
    // ---- P1: assemble hW (from partials) + attention scores ----
    if (tid < 256) {
      float a = 0.f;
      if (t == 0) {
        const float* hr = hbuf + (size_t)b1 * 256;
        for (int k = 0; k < 256; ++k) a += hr[k] * w_attn[(size_t)tid * 1024 + 512 + k];
      } else {
        for (int gg = 0; gg < 32; ++gg) a += ws[OFF_HWP + ((size_t)gg * 8 + b1) * 256 + tid];
      }
      hw_s[tid] = a;
    }
    __syncthreads();
    for (int s = w1; s < 50; s += 8) {
      float cv = cov[b1 * 200 + s0 + s];
      float4 e4 = *(const float4*)(&ep_s[s * 256 + jb4]);
      float4 h4 = *(const float4*)(&hw_s[jb4]);
      float t0 = tanh_fast(e4.x + h4.x + cv * wcp4.x + bcp4.x);
      float t1 = tanh_fast(e4.y + h4.y + cv * wcp4.y + bcp4.y);
      float t2 = tanh_fast(e4.z + h4.z + cv * wcp4.z + bcp4.z);
      float t3 = tanh_fast(e4.w + h4.w + cv * wcp4.w + bcp4.w);
      float p = t0 * wav4.x + t1 * wav4.y + t2 * wav4.z + t3 * wav4.w;
#pragma unroll
      for (int md = 1; md < 64; md <<= 1) p += __shfl_xor(p, md);
      if (lane == 0) scores[b1 * 200 + s0 + s] = p;
    }
    grid_barrier(bar, bar + 1, 32);

    // ---- P2 (blocks 0..7, one per batch): softmax/mask/renorm/cov/ctx ----
    if (g < 8) {
      const int b = g;
      if (tid < 256) sc_s[tid] = (tid < 200) ? scores[b * 200 + tid] : -1e30f;
      __syncthreads();
      if (tid < 256) red_s[tid] = sc_s[tid];
      __syncthreads();
      for (int st = 128; st >= 1; st >>= 1) { if (tid < st) red_s[tid] = fmaxf(red_s[tid], red_s[tid + st]); __syncthreads(); }
      float mx = red_s[0];
      __syncthreads();
      if (tid < 256) { float e = (tid < 200) ? __expf(sc_s[tid] - mx) : 0.f; sc_s[tid] = e; red_s[tid] = e; }
      __syncthreads();
      for (int st = 128; st >= 1; st >>= 1) { if (tid < st) red_s[tid] += red_s[tid + st]; __syncthreads(); }
      float sum = red_s[0];
      __syncthreads();
      if (tid < 256) {
        float a = 0.f;
        if (tid < 200) a = (sc_s[tid] / sum) * ws[OFF_MASK + b * 200 + tid];
        at_s[tid] = a; red_s[tid] = a;
      }
      __syncthreads();
      for (int st = 128; st >= 1; st >>= 1) { if (tid < st) red_s[tid] += red_s[tid + st]; __syncthreads(); }
      float rs = red_s[0] + 1e-10f;
      __syncthreads();
      if (tid < 200) {
        float attn = at_s[tid] / rs;
        at_s[tid] = attn;
        cov[b * 200 + tid] += attn;
        ws[OFF_AS + ((size_t)t * 8 + b) * 200 + tid] = attn;
      }
      __syncthreads();
      // ctx = sum_s attn_s * enc_out[b][s][:]
      const int sq2 = tid >> 7, d4 = (tid & 127) * 4;
      float4 ca = {0.f, 0.f, 0.f, 0.f};
      for (int s = sq2 * 50; s < sq2 * 50 + 50; ++s) {
        float a = at_s[s];
        float4 eo = *(const float4*)(ws + OFF_ENCOUT + ((size_t)b * 200 + s) * 512 + d4);
        ca.x += a * eo.x; ca.y += a * eo.y; ca.z += a * eo.z; ca.w += a * eo.w;
      }
      *(float4*)(&ctxp[sq2][d4]) = ca;
      __syncthreads();
      {
        int d = tid;
        float c = ctxp[0][d] + ctxp[1][d] + ctxp[2][d] + ctxp[3][d];
        hcat[(size_t)b * 768 + d] = c;
        ws[OFF_CS + ((size_t)t * 8 + b) * 512 + d] = c;
      }
      if (tid < 256) hcat[(size_t)b * 768 + 512 + tid] = hbuf[(size_t)b * 256 + tid];
    }
    grid_barrier(bar, bar + 1, 32);

    // ---- P3 (all 32): gates over K=768 ([ctx;h]) + cell update + hW partials ----
    {
      const float* hc  = hcat + (size_t)bu * 768;
      const float* wr1 = wih_d + (size_t)j * 768 + 256 + kc * 256;   // ctx cols
      const float* hc1 = hc + kc * 256;
      float acc = 0.f;
#pragma unroll 8
      for (int kk = 0; kk < 256; kk += 4) {
        float4 w = *(const float4*)(wr1 + kk);
        float4 h = *(const float4*)(hc1 + kk);
        acc += w.x * h.x + w.y * h.y + w.z * h.z + w.w * h.w;
      }
      const float* wr2 = whh_d + (size_t)j * 256 + kc * 128;
      const float* hc2 = hc + 512 + kc * 128;
#pragma unroll 8
      for (int kk = 0; kk < 128; kk += 4) {
        float4 w = *(const float4*)(wr2 + kk);
        float4 h = *(const float4*)(hc2 + kk);
        acc += w.x * h.x + w.y * h.y + w.z * h.z + w.w * h.w;
      }
      acc += __shfl_xor(acc, 1);  // combine kc halves
      float z = ws[OFF_DPRE + ((size_t)t * 8 + b3) * 1024 + j] + acc;
      float y1 = __shfl_xor(z, 2);
      float y2 = __shfl_xor(z, 4);
      float y3 = __shfl_xor(z, 6);
      float zi = pick4(z, y1, y2, y3, gate);
      float zf = pick4(z, y1, y2, y3, gate ^ 1);
      float zg = pick4(z, y1, y2, y3, gate ^ 2);
      float zo = pick4(z, y1, y2, y3, gate ^ 3);
      float cn = sigf(zf) * c_reg + sigf(zi) * tanh_fast(zg);
      float hn = sigf(zo) * tanh_fast(cn);
      c_reg = cn;
      if (gate == 0 && kc == 0) {
        hbuf[(size_t)b3 * 256 + u] = hn;
        ws[OFF_HS + ((size_t)t * 8 + b3) * 256 + u] = hn;
        h_s[u_l * 8 + b3] = hn;
      }
    }
    __syncthreads();
    // hW partials for next step: hWp[g][b][j] = sum_{ul} h_s[ul][b] * w_attn[j][512+g*8+ul]
    {
      int jj = tid >> 1, b0 = (tid & 1) * 4;
      const float* wa = w_attn + (size_t)jj * 1024 + 512 + g * 8;
      float w0 = wa[0], w1b = wa[1], w2 = wa[2], w3 = wa[3], w4 = wa[4], w5 = wa[5], w6 = wa[6], w7 = wa[7];
      for (int bb = b0; bb < b0 + 4; ++bb) {
        float a = h_s[0 * 8 + bb] * w0 + h_s[1 * 8 + bb] * w1b + h_s[2 * 8 + bb] * w2 + h_s[3 * 8 + bb] * w3
                + h_s[4 * 8 + bb] * w4 + h_s[5 * 8 + bb] * w5 + h_s[6 * 8 + bb] * w6 + h_s[7 * 8 + bb] * w7;
        ws[OFF_HWP + ((size_t)g * 8 + bb) * 256 + jj] = a;
      }
    }
    grid_barrier(bar, bar + 1, 32);
  }
}

__global__ __launch_bounds__(64) void k_pgen(const float* w_ptr, const float* b_ptr, float* ws) {
  int r = blockIdx.x, lane = threadIdx.x;
  float p = 0.f;
#pragma unroll
  for (int i = 0; i < 12; ++i) {
    int k = lane + 64 * i;
    float v = (k < 512) ? ws[OFF_CS + (size_t)r * 512 + k]
                        : ws[OFF_HS + (size_t)r * 256 + (k - 512)];
    p += v * w_ptr[k];
  }
#pragma unroll
  for (int m = 1; m < 64; m <<= 1) p += __shfl_xor(p, m);
  if (lane == 0) ws[OFF_PG + r] = sigf(p + b_ptr[0]);
}

// ---------------- fused vocab softmax + pointer scatter + CE loss (in-place on d_out) ----------------
__global__ __launch_bounds__(256) void k_v2(const int* xin, const int* labels, float* ws, float* out) {
  __shared__ float redm[256], reds[256];
  __shared__ int xv[200];
  __shared__ float s1sh, corrsh;
  int r = blockIdx.x, tid = threadIdx.x;
  int tt = r >> 3, b = r & 7;
  float* row = out + (size_t)(b * 50 + tt) * 64000;
  for (int i = tid; i < 200; i += 256) xv[i] = xin[b * 200 + i];
  // pass 1: online max/sum over logits z
  float m = -1e30f, s = 0.f;
  for (int i = tid; i < 32000; i += 256) {
    float z = row[i];
    float nm = fmaxf(m, z);
    s = s * __expf(m - nm) + __expf(z - nm);
    m = nm;
  }
  redm[tid] = m; reds[tid] = s;
  __syncthreads();
  for (int st = 128; st >= 1; st >>= 1) {
    if (tid < st) {
      float m2 = redm[tid + st], s2 = reds[tid + st];
      float M = fmaxf(redm[tid], m2);
      reds[tid] = reds[tid] * __expf(redm[tid] - M) + s2 * __expf(m2 - M);
      redm[tid] = M;
    }
    __syncthreads();
  }
  float mx = redm[0], sum = reds[0];
  float pg = ws[OFF_PG + r];
  __syncthreads();
  // pass 2: write dist = pg*softmax(z), zero upper half, accumulate sum(exp(dist))
  float s1 = 0.f;
  float inv = 1.0f / sum;
  for (int i = tid; i < 32000; i += 256) {
    float z = row[i];
    float d = pg * (__expf(z - mx) * inv);
    row[i] = d;
    s1 += __expf(d);
  }
  for (int i = 32000 + tid; i < 64000; i += 256) row[i] = 0.0f;
  reds[tid] = s1;
  __syncthreads();
  for (int st = 128; st >= 1; st >>= 1) { if (tid < st) reds[tid] += reds[tid + st]; __syncthreads(); }
  if (tid == 0) { s1sh = reds[0]; corrsh = 0.f; }
  __syncthreads();
  // scatter (1-pg)*attn at x positions; merge duplicates so each v has one owner
  if (tid < 200) {
    int v = xv[tid];
    bool own = true;
    for (int s2 = 0; s2 < tid; ++s2) if (xv[s2] == v) { own = false; break; }
    if (own) {
      float delta = 0.f;
      for (int s2 = tid; s2 < 200; ++s2)
        if (xv[s2] == v) delta += ws[OFF_AS + (size_t)r * 200 + s2];
      delta *= (1.0f - pg);
      float base = row[v];
      row[v] = base + delta;
      atomicAdd(&corrsh, __expf(base + delta) - __expf(base));
    }
  }
  __syncthreads();
  if (tid == 0) {
    float lse = logf(s1sh + corrsh + 32000.0f);   // +32000 for the exp(0) upper half
    int tgt = labels[b * 51 + tt + 1];
    float dt = row[tgt];
    float valid = (tgt != 0) ? 1.f : 0.f;
    atomicAdd(ws + OFF_ACC + 0, valid * (lse - dt));
    atomicAdd(ws + OFF_ACC + 1, valid);
  }
}

__global__ void k_loss(float* ws, float* out, int out_size) {
  out[out_size - 1] = ws[OFF_ACC + 0] / ws[OFF_ACC + 1] + ws[OFF_ACC + 2] / ws[OFF_ACC + 3];
}

// ---------------- launch ----------------
extern "C" void kernel_launch(void* const* d_in, const int* in_sizes, int n_in,
                              void* d_out, int out_size, void* d_ws, size_t ws_size,
                              hipStream_t stream) {
  (void)in_sizes; (void)n_in; (void)ws_size;
  const int*   x       = (const int*)  d_in[0];
  const int*   labels  = (const int*)  d_in[1];
  const float* emb_enc = (const float*)d_in[3];
  const float* wih_f   = (const float*)d_in[4];
  const float* whh_f   = (const float*)d_in[5];
  const float* bih_f   = (const float*)d_in[6];
  const float* bhh_f   = (const float*)d_in[7];
  const float* wih_b   = (const float*)d_in[8];
  const float* whh_b   = (const float*)d_in[9];
  const float* bih_b   = (const float*)d_in[10];
  const float* bhh_b   = (const float*)d_in[11];
  const float* w_sel1  = (const float*)d_in[12];
  const float* b_sel1  = (const float*)d_in[13];
  const float* w_sel2  = (const float*)d_in[14];
  const float* b_sel2  = (const float*)d_in[15];
  const float* w_rh    = (const float*)d_in[16];
  const float* b_rh    = (const float*)d_in[17];
  const float* w_rc    = (const float*)d_in[18];
  const float* b_rc    = (const float*)d_in[19];
  const float* emb_dec = (const float*)d_in[20];
  const float* wih_d   = (const float*)d_in[21];
  const float* whh_d   = (const float*)d_in[22];
  const float* bih_d   = (const float*)d_in[23];
  const float* bhh_d   = (const float*)d_in[24];
  const float* w_attn  = (const float*)d_in[25];
  const float* b_attn  = (const float*)d_in[26];
  const float* w_attn_v= (const float*)d_in[27];
  const float* w_ptr   = (const float*)d_in[28];
  const float* b_ptr   = (const float*)d_in[29];
  const float* w_gen   = (const float*)d_in[30];
  const float* b_gen   = (const float*)d_in[31];
  const float* w_cov   = (const float*)d_in[32];
  const float* b_cov   = (const float*)d_in[33];
  float* ws  = (float*)d_ws;
  float* out = (float*)d_out;

  hipMemsetAsync(d_ws, 0, ZERO_FLOATS * 4, stream);
  k_biassum<<<12, 256, 0, stream>>>(bih_f, bhh_f, bih_b, bhh_b, bih_d, bhh_d, ws);
  k_embed<<<2000, 256, 0, stream>>>(x, labels, emb_enc, emb_dec, ws);
  k_gemm<64,64,4,4,0,0><<<dim3(25,16), 256, 0, stream>>>(ws+OFF_EMB,  wih_f, ws+OFF_BIAS,      ws+OFF_PREF, 1600, 256, 256, 1024);
  k_gemm<64,64,4,4,0,0><<<dim3(25,16), 256, 0, stream>>>(ws+OFF_EMBR, wih_b, ws+OFF_BIAS+1024, ws+OFF_PREB, 1600, 256, 256, 1024);
  k_gemm<64,64,4,4,0,0><<<dim3(7,16),  256, 0, stream>>>(ws+OFF_DEMB, wih_d, ws+OFF_BIAS+2048, ws+OFF_DPRE, 400,  256, 768, 1024);
  k_encoder<<<32, 512, 0, stream>>>(whh_f, whh_b, ws);
  k_gemm<64,64,4,4,0,1><<<dim3(25,4),  256, 0, stream>>>(ws+OFF_ENCOUT, w_sel1, b_sel1, ws+OFF_HSEL, 1600, 512, 512, 256);
  k_selbce<<<1600, 64, 0, stream>>>(w_sel2, b_sel2, x, ws);
  k_gemm<64,64,4,4,0,0><<<dim3(25,4),  256, 0, stream>>>(ws+OFF_ENCOUT, w_attn, b_attn, ws+OFF_EP, 1600, 512, 1024, 256);
  k_wcp<<<1, 256, 0, stream>>>(w_attn, w_cov, b_cov, ws);
  k_h0c0<<<8, 256, 0, stream>>>(w_rh, b_rh, w_rc, b_rc, ws);
  k_decoder<<<32, 512, 0, stream>>>(wih_d, whh_d, w_attn, w_attn_v, ws);
  k_pgen<<<400, 64, 0, stream>>>(w_ptr, b_ptr, ws);
  k_gemm<128,128,8,8,1,0><<<dim3(4,250), 256, 0, stream>>>(ws+OFF_HS, w_gen, b_gen, out, 400, 256, 256, 64000);
  k_v2<<<400, 256, 0, stream>>>(x, labels, ws, out);
  k_loss<<<1, 1, 0, stream>>>(ws, out, out_size);
}

// Round 2
// 3834.282 us; speedup vs baseline: 2.1063x; 2.1063x over previous
//
#include <hip/hip_runtime.h>
#include <hip/hip_bf16.h>
#include <stdint.h>

// B=8, S=200, H=256, V=32000, T=51. out = (8,50,64000) fp32 + scalar loss.

#define DEVI __device__ __forceinline__
#define AT_RLX __ATOMIC_RELAXED
#define AT_REL __ATOMIC_RELEASE
#define SC_AGT __HIP_MEMORY_SCOPE_AGENT

// ---------------- ws layout (float offsets), ~23.7 MB ----------------
static constexpr size_t OFF_ACC   = 0;        // 4: nll_sum, valid_sum, bce_sum, m_sum
static constexpr size_t OFF_FLAGE = 4;        // 32 ints (encoder flags, 16/dir)
static constexpr size_t OFF_FLAGD = 36;       // 32 ints (decoder flags)
static constexpr size_t OFF_STAT  = 68;       // 32*4 softmax stats
static constexpr size_t ZERO_FLOATS = 200;
static constexpr size_t OFF_CTX   = 256;      // 8*512 ctx accumulators
static constexpr size_t OFF_EMB   = 4352;     // [t][b][h] 200*8*256 (later reused as HSEL)
static constexpr size_t OFF_HSEL  = OFF_EMB;  // alias (EMB dead after pre-GEMMs)
static constexpr size_t OFF_PREF  = OFF_EMB  + 409600;   // 1638400
static constexpr size_t OFF_PREB  = OFF_PREF + 1638400;  // 1638400
static constexpr size_t OFF_BIAS  = OFF_PREB + 1638400;  // 3072
static constexpr size_t OFF_HB    = OFF_BIAS + 3072;     // enc h dbl buf [buf][dir][2048] = 8192
static constexpr size_t OFF_HFIN  = OFF_HB   + 8192;     // 4096
static constexpr size_t OFF_CFIN  = OFF_HFIN + 4096;     // 4096
static constexpr size_t OFF_ENCOUT= OFF_CFIN + 4096;     // [b][s][512] = 819200
static constexpr size_t OFF_MASK  = OFF_ENCOUT + 819200; // 1600
static constexpr size_t OFF_C0    = OFF_MASK + 1600;     // 2048
static constexpr size_t OFF_EP    = OFF_C0   + 2048;     // [b][s][256] = 409600
static constexpr size_t OFF_WCP   = OFF_EP   + 409600;   // 256
static constexpr size_t OFF_BCP   = OFF_WCP  + 256;      // 256
static constexpr size_t OFF_DEMB  = OFF_BCP  + 256;      // 50*8*256 = 102400
static constexpr size_t OFF_DPRE  = OFF_DEMB + 102400;   // 50*8*1024 = 409600
static constexpr size_t OFF_HBUF  = OFF_DPRE + 409600;   // dec h dbl buf [2][2048] = 4096
static constexpr size_t OFF_CS    = OFF_HBUF + 4096;     // [t][b][512] = 204800
static constexpr size_t OFF_HS    = OFF_CS   + 204800;   // [t][b][256] = 102400
static constexpr size_t OFF_AS    = OFF_HS   + 102400;   // [t][b][200] = 80000
static constexpr size_t OFF_PG    = OFF_AS   + 80000;    // 400 (pad 512)
static constexpr size_t OFF_WAT   = OFF_PG   + 512;      // waT[k][jj] 256*256 = 65536

// ---------------- helpers ----------------
DEVI float sigf(float x)      { return 1.0f / (1.0f + __expf(-x)); }
DEVI float tanh_fast(float x) { return 1.0f - 2.0f / (1.0f + __expf(2.0f * x)); }
DEVI float pick4(float z, float x1, float x2, float x3, int mm) {
  return mm == 0 ? z : (mm == 1 ? x1 : (mm == 2 ? x2 : x3));
}
DEVI float ald(const float* p)  { return __hip_atomic_load((float*)p, AT_RLX, SC_AGT); }
DEVI void  ast(float* p, float v){ __hip_atomic_store(p, v, AT_RLX, SC_AGT); }

// Distributed flag barrier: no RMW, no fences beyond one release store.
DEVI void fbar(int* flags, int g, int n, int val) {
  __syncthreads();   // drains vmcnt -> all prior (atomic) stores globally visible
  if ((int)threadIdx.x == 0)
    __hip_atomic_store(flags + g, val, AT_REL, SC_AGT);
  if ((int)threadIdx.x < n && (int)threadIdx.x != g) {
    while (__hip_atomic_load(flags + threadIdx.x, AT_RLX, SC_AGT) < val)
      __builtin_amdgcn_s_sleep(2);
  }
  __syncthreads();
}

// ---------------- small prep kernels ----------------
__global__ __launch_bounds__(256) void k_biassum(
    const float* bih_f, const float* bhh_f, const float* bih_b, const float* bhh_b,
    const float* bih_d, const float* bhh_d, float* ws) {
  int i = blockIdx.x * 256 + threadIdx.x;
  int which = i >> 10, jj = i & 1023;
  float v = (which == 0) ? bih_f[jj] + bhh_f[jj]
          : (which == 1) ? bih_b[jj] + bhh_b[jj]
                         : bih_d[jj] + bhh_d[jj];
  ws[OFF_BIAS + i] = v;
}

__global__ __launch_bounds__(256) void k_embed(
    const int* xin, const int* labels, const float* emb_enc, const float* emb_dec, float* ws) {
  int r = blockIdx.x, h = threadIdx.x;
  if (r < 1600) {
    int t = r >> 3, b = r & 7;
    ws[OFF_EMB + (size_t)r * 256 + h] = emb_enc[(size_t)xin[b * 200 + t] * 256 + h];
  } else {
    int r2 = r - 1600;
    int t = r2 >> 3, b = r2 & 7;
    int tok = (t == 0) ? 1 : labels[b * 51 + t];
    ws[OFF_DEMB + (size_t)r2 * 256 + h] = emb_dec[(size_t)tok * 256 + h];
  }
}

// waT[k][jj] = w_attn[jj][512+k]
__global__ __launch_bounds__(256) void k_wat(const float* w_attn, float* ws) {
  int k = blockIdx.x, jj = threadIdx.x;
  ws[OFF_WAT + (size_t)k * 256 + jj] = w_attn[(size_t)jj * 1024 + 512 + k];
}

// ---------------- tiled SGEMM: C[m][n] = act(sum_k A[m][k]*B[n][k] + bias[n]) ----------------
template<int BM, int BN, int TM, int TN, int CMAP, int ACT, int AMAP>
__global__ __launch_bounds__(256) void k_gemm(
    const float* __restrict__ A, const float* __restrict__ B,
    const float* __restrict__ bias, float* __restrict__ C,
    int M, int K, int ldb, int ldc) {
  __shared__ float As[16][BM];
  __shared__ float Bs[16][BN];
  const int tid = threadIdx.x;
  const int tx = tid & 15, ty = tid >> 4;
  const int m0 = blockIdx.x * BM, n0 = blockIdx.y * BN;
  float acc[TM][TN];
#pragma unroll
  for (int i = 0; i < TM; ++i)
#pragma unroll
    for (int q = 0; q < TN; ++q) acc[i][q] = 0.f;

  for (int kk = 0; kk < K; kk += 16) {
#pragma unroll
    for (int e = tid; e < BM * 4; e += 256) {
      int m = e >> 2, k4 = (e & 3) * 4;
      int gm0 = m0 + m;
      float4 v = {0.f, 0.f, 0.f, 0.f};
      if (gm0 < M) {
        int gm = AMAP ? (((199 - (gm0 >> 3)) << 3) + (gm0 & 7)) : gm0;
        v = *(const float4*)(A + (size_t)gm * K + kk + k4);
      }
      As[k4 + 0][m] = v.x; As[k4 + 1][m] = v.y; As[k4 + 2][m] = v.z; As[k4 + 3][m] = v.w;
    }
#pragma unroll
    for (int e = tid; e < BN * 4; e += 256) {
      int n = e >> 2, k4 = (e & 3) * 4;
      float4 v = *(const float4*)(B + (size_t)(n0 + n) * ldb + kk + k4);
      Bs[k4 + 0][n] = v.x; Bs[k4 + 1][n] = v.y; Bs[k4 + 2][n] = v.z; Bs[k4 + 3][n] = v.w;
    }
    __syncthreads();
#pragma unroll
    for (int k = 0; k < 16; ++k) {
      float a[TM], bv[TN];
#pragma unroll
      for (int i = 0; i < TM; ++i) a[i] = As[k][ty * TM + i];
#pragma unroll
      for (int q = 0; q < TN; ++q) bv[q] = Bs[k][tx * TN + q];
#pragma unroll
      for (int i = 0; i < TM; ++i)
#pragma unroll
        for (int q = 0; q < TN; ++q) acc[i][q] += a[i] * bv[q];
    }
    __syncthreads();
  }
#pragma unroll
  for (int i = 0; i < TM; ++i) {
    int gm = m0 + ty * TM + i;
    if (gm >= M) continue;
    size_t base;
    if (CMAP == 1) { int t = gm >> 3, b = gm & 7; base = (size_t)(b * 50 + t) * 64000; }
    else            base = (size_t)gm * ldc;
#pragma unroll
    for (int q = 0; q < TN; ++q) {
      int n = n0 + tx * TN + q;
      float v = acc[i][q] + bias[n];
      if (ACT == 1) v = tanh_fast(v);
      C[base + n] = v;
    }
  }
}

// ---------------- encoder: 32 blocks (16/dir), weights in registers ----------------
// Block (dir,p): units u0..u0+16, 4 gates -> 64 rows. Thread (r=tid>>3, kc=tid&7):
// holds W[j(r)][kc*32..+32) in regs. Reduce-scatter over kc via shuffles.
__global__ __launch_bounds__(512, 1) void k_encoder(
    const float* __restrict__ whh_f, const float* __restrict__ whh_b, float* __restrict__ ws) {
  __shared__ float hs[8 * 288];   // staged h, 32-chunks padded to 36
  __shared__ float zs[512];
  const int dir = blockIdx.x >> 4;
  const int p   = blockIdx.x & 15;
  const int u0  = p * 16;
  const float* whh = dir ? whh_b : whh_f;
  const float* pre = ws + (dir ? OFF_PREB : OFF_PREF);
  int* flags = (int*)(ws + OFF_FLAGE) + dir * 16;
  const int tid = threadIdx.x;
  const int r = tid >> 3, kc = tid & 7;
  const int gt = r >> 4, ui = r & 15;
  const int j = gt * 256 + u0 + ui;
  float4 W[8];
  {
    const float* wr = whh + (size_t)j * 256 + kc * 32;
#pragma unroll
    for (int q = 0; q < 8; ++q) W[q] = *(const float4*)(wr + q * 4);
  }
  const int ui2 = tid & 15, b2 = tid >> 4;   // cell-update role, tid<128
  float c_reg = 0.f;
  float* hBa = ws + OFF_HB;
  float* enc = ws + OFF_ENCOUT;

  for (int t = 0; t < 200; ++t) {
    float pre_v = pre[((size_t)t * 8 + kc) * 1024 + j];
    float acc[8];
#pragma unroll
    for (int b = 0; b < 8; ++b) acc[b] = 0.f;
    if (t > 0) {
      {
        float* src = hBa + (size_t)((((t + 1) & 1) * 2 + dir) * 2048) + tid * 4;
        float v0 = ald(src + 0);
        float v1 = ald(src + 1);
        float v2 = ald(src + 2);
        float v3 = ald(src + 3);
        int kk0 = (tid * 4) & 255, bb = tid >> 6;
        float* dst = &hs[bb * 288 + (kk0 >> 5) * 36 + (kk0 & 31)];
        dst[0] = v0; dst[1] = v1; dst[2] = v2; dst[3] = v3;
      }
      __syncthreads();
      const float* hrow = &hs[kc * 36];
#pragma unroll
      for (int b = 0; b < 8; ++b) {
        const float* hbp = hrow + b * 288;
#pragma unroll
        for (int q = 0; q < 8; ++q) {
          float4 h4 = *(const float4*)(hbp + q * 4);
          acc[b] = fmaf(W[q].x, h4.x, acc[b]);
          acc[b] = fmaf(W[q].y, h4.y, acc[b]);
          acc[b] = fmaf(W[q].z, h4.z, acc[b]);
          acc[b] = fmaf(W[q].w, h4.w, acc[b]);
        }
      }
    }
    // reduce-scatter over kc (xor 4,2,1): ends with acc[0] = full sum for b=kc
    {
      bool h4b = (kc & 4) != 0;
#pragma unroll
      for (int i = 0; i < 4; ++i) {
        float send = h4b ? acc[i] : acc[i + 4];
        float keep = h4b ? acc[i + 4] : acc[i];
        acc[i] = keep + __shfl_xor(send, 4);
      }
      bool h2b = (kc & 2) != 0;
#pragma unroll
      for (int i = 0; i < 2; ++i) {
        float send = h2b ? acc[i] : acc[i + 2];
        float keep = h2b ? acc[i + 2] : acc[i];
        acc[i] = keep + __shfl_xor(send, 2);
      }
      bool h1b = (kc & 1) != 0;
      {
        float send = h1b ? acc[0] : acc[1];
        float keep = h1b ? acc[1] : acc[0];
        acc[0] = keep + __shfl_xor(send, 1);
      }
    }
    zs[tid] = acc[0] + pre_v;   // zs[r*8 + b]
    __syncthreads();
    if (tid < 128) {
      int i0 = ui2 * 8 + b2;
      float zi = zs[i0], zf = zs[128 + i0], zg = zs[256 + i0], zo = zs[384 + i0];
      float cn = sigf(zf) * c_reg + sigf(zi) * tanh_fast(zg);
      float hn = sigf(zo) * tanh_fast(cn);
      c_reg = cn;
      int uu = u0 + ui2;
      ast(hBa + (size_t)(((t & 1) * 2 + dir) * 2048) + b2 * 256 + uu, hn);
      int s = dir ? (199 - t) : t;
      enc[((size_t)b2 * 200 + s) * 512 + dir * 256 + uu] = hn;
      if (t == 199) {
        ws[OFF_HFIN + (size_t)(dir * 8 + b2) * 256 + uu] = hn;
        ws[OFF_CFIN + (size_t)(dir * 8 + b2) * 256 + uu] = cn;
      }
    }
    if (t < 199) fbar(flags, p, 16, t + 1);
  }
}

// ---------------- copy-prob head + BCE ----------------
__global__ __launch_bounds__(64) void k_selbce(
    const float* w_sel2, const float* b_sel2, const int* xin, float* ws) {
  int r = blockIdx.x, lane = threadIdx.x;
  float pacc = 0.f;
#pragma unroll
  for (int i = 0; i < 4; ++i) {
    int k = lane + 64 * i;
    pacc += ws[OFF_HSEL + (size_t)r * 256 + k] * w_sel2[k];
  }
#pragma unroll
  for (int m = 1; m < 64; m <<= 1) pacc += __shfl_xor(pacc, m);
  if (lane == 0) {
    float cp = sigf(pacc + b_sel2[0]);
    ws[OFF_MASK + r] = (cp > 1e-8f) ? 1.f : 0.f;
    int b = r / 200, s = r % 200;
    float m = (xin[b * 200 + s] != 0) ? 1.f : 0.f;
    if (m > 0.f) {
      float lp = fmaxf(logf(cp), -100.f);
      atomicAdd(ws + OFF_ACC + 2, -lp);
    }
    atomicAdd(ws + OFF_ACC + 3, m);
  }
}

__global__ __launch_bounds__(256) void k_wcp(
    const float* w_attn, const float* w_cov, const float* b_cov, float* ws) {
  int jj = threadIdx.x;
  float a = 0.f, c = 0.f;
  for (int h = 0; h < 256; ++h) {
    float w = w_attn[(size_t)jj * 1024 + 768 + h];
    a += w * w_cov[h];
    c += w * b_cov[h];
  }
  ws[OFF_WCP + jj] = a;
  ws[OFF_BCP + jj] = c;
}

__global__ __launch_bounds__(256) void k_h0c0(
    const float* w_rh, const float* b_rh, const float* w_rc, const float* b_rc, float* ws) {
  int b = blockIdx.x, jj = threadIdx.x;
  const float* hf  = ws + OFF_HFIN + (size_t)b * 256;
  const float* hbk = ws + OFF_HFIN + 2048 + (size_t)b * 256;
  const float* cf  = ws + OFF_CFIN + (size_t)b * 256;
  const float* cbk = ws + OFF_CFIN + 2048 + (size_t)b * 256;
  float ah = b_rh[jj], ac = b_rc[jj];
  for (int k = 0; k < 256; ++k) {
    ah += hf[k] * w_rh[(size_t)jj * 512 + k];
    ac += cf[k] * w_rc[(size_t)jj * 512 + k];
  }
  for (int k = 0; k < 256; ++k) {
    ah += hbk[k] * w_rh[(size_t)jj * 512 + 256 + k];
    ac += cbk[k] * w_rc[(size_t)jj * 512 + 256 + k];
  }
  ws[OFF_C0 + (size_t)b * 256 + jj] = fmaxf(ac, 0.f);
  ws[OFF_HBUF + (size_t)b * 256 + jj] = fmaxf(ah, 0.f);   // dec h buf0
}

// ---------------- decoder: 32 blocks, 3 flag-barriers/step, all-atomic exchange ----------------
__global__ __launch_bounds__(512, 1) void k_decoder(
    const float* __restrict__ wih_d, const float* __restrict__ whh_d,
    const float* __restrict__ w_attn_v, float* __restrict__ ws) {
  __shared__ float hb_s[256], hw_s[256];
  __shared__ float sc_s[64], msk_s[64], cv_s[64], at_s[64];
  __shared__ float st_s[12], mS_s[2];
  __shared__ float ctxp[4][512];
  __shared__ float hc_s[6144];
  const int g = blockIdx.x, tid = threadIdx.x;
  const int lane = tid & 63, w1 = tid >> 6;
  const int b1 = g >> 2, sq = g & 3, s0 = sq * 50;
  int* flags = (int*)(ws + OFF_FLAGD);
  // P3 role
  const int kc = lane & 1, gate = (lane >> 1) & 3, u_l = lane >> 3;
  const int b3 = w1;
  const int u = g * 8 + u_l, j = gate * 256 + u;
  const int jb4 = lane * 4;
  float4 wcp4 = *(const float4*)(ws + OFF_WCP + jb4);
  float4 bcp4 = *(const float4*)(ws + OFF_BCP + jb4);
  float4 wav4 = *(const float4*)(w_attn_v + jb4);
  float c_reg = ws[OFF_C0 + (size_t)b3 * 256 + u];
  if (tid < 64) {
    msk_s[tid] = (tid < 50) ? ws[OFF_MASK + b1 * 200 + s0 + tid] : 0.f;
    cv_s[tid] = 0.f;
  }
  __syncthreads();

  for (int t = 0; t < 50; ++t) {
    const int rb = t & 1, wb = 1 - rb;
    // ---- P1: zero ctx slice, stage h[b1], hW, scores, local softmax stats ----
    if (tid < 128) ast(ws + OFF_CTX + g * 128 + tid, 0.f);
    if (tid < 256) hb_s[tid] = ald(ws + OFF_HBUF + rb * 2048 + b1 * 256 + tid);
    __syncthreads();
    if (tid < 256) {
      float a = 0.f;
      const float* wt = ws + OFF_WAT + tid;
      for (int k = 0; k < 256; k += 4) {
        a = fmaf(hb_s[k],     wt[(size_t)k * 256],       a);
        a = fmaf(hb_s[k + 1], wt[(size_t)(k + 1) * 256], a);
        a = fmaf(hb_s[k + 2], wt[(size_t)(k + 2) * 256], a);
        a = fmaf(hb_s[k + 3], wt[(size_t)(k + 3) * 256], a);
      }
      hw_s[tid] = a;
    }
    __syncthreads();
    for (int s = w1; s < 50; s += 8) {
      float cv = cv_s[s];
      float4 e4 = *(const float4*)(ws + OFF_EP + ((size_t)(b1 * 200 + s0 + s)) * 256 + jb4);
      float4 h4 = *(const float4*)(&hw_s[jb4]);
      float t0 = tanh_fast(e4.x + h4.x + cv * wcp4.x + bcp4.x);
      float t1 = tanh_fast(e4.y + h4.y + cv * wcp4.y + bcp4.y);
      float t2 = tanh_fast(e4.z + h4.z + cv * wcp4.z + bcp4.z);
      float t3 = tanh_fast(e4.w + h4.w + cv * wcp4.w + bcp4.w);
      float pp = t0 * wav4.x + t1 * wav4.y + t2 * wav4.z + t3 * wav4.w;
#pragma unroll
      for (int md = 1; md < 64; md <<= 1) pp += __shfl_xor(pp, md);
      if (lane == 0) sc_s[s] = pp;
    }
    __syncthreads();
    if (tid < 64) {
      float v = (tid < 50) ? sc_s[tid] : -1e30f;
      float mx = v;
#pragma unroll
      for (int m = 1; m < 64; m <<= 1) mx = fmaxf(mx, __shfl_xor(mx, m));
      float e = (tid < 50) ? __expf(v - mx) : 0.f;
      float es = e, ems = e * msk_s[tid];
#pragma unroll
      for (int m = 1; m < 64; m <<= 1) { es += __shfl_xor(es, m); ems += __shfl_xor(ems, m); }
      if (tid == 0) {
        ast(ws + OFF_STAT + g * 4 + 0, mx);
        ast(ws + OFF_STAT + g * 4 + 1, es);
        ast(ws + OFF_STAT + g * 4 + 2, ems);
      }
    }
    fbar(flags, g, 32, 3 * t + 1);

    // ---- P2: global softmax combine, attn, coverage, ctx partial ----
    if (tid < 12) st_s[tid] = ald(ws + OFF_STAT + (size_t)(b1 * 4 + tid / 3) * 4 + tid % 3);
    __syncthreads();
    if (tid == 0) {
      float m = fmaxf(fmaxf(st_s[0], st_s[3]), fmaxf(st_s[6], st_s[9]));
      float e0 = __expf(st_s[0] - m), e1 = __expf(st_s[3] - m), e2 = __expf(st_s[6] - m), e3 = __expf(st_s[9] - m);
      float S  = st_s[1] * e0 + st_s[4] * e1 + st_s[7] * e2 + st_s[10] * e3;
      float MS = st_s[2] * e0 + st_s[5] * e1 + st_s[8] * e2 + st_s[11] * e3;
      mS_s[0] = m; mS_s[1] = 1.0f / (MS + 1e-10f * S);
    }
    __syncthreads();
    if (tid < 50) {
      float a = __expf(sc_s[tid] - mS_s[0]) * msk_s[tid] * mS_s[1];
      at_s[tid] = a;
      cv_s[tid] += a;
      ws[OFF_AS + ((size_t)t * 8 + b1) * 200 + s0 + tid] = a;   // plain: post-kernel consumer
    }
    __syncthreads();
    {
      int d4 = (tid & 127) * 4, sh = tid >> 7;
      float4 ca = {0.f, 0.f, 0.f, 0.f};
      for (int s = sh; s < 50; s += 4) {
        float a = at_s[s];
        float4 eo = *(const float4*)(ws + OFF_ENCOUT + ((size_t)(b1 * 200 + s0 + s)) * 512 + d4);
        ca.x = fmaf(a, eo.x, ca.x); ca.y = fmaf(a, eo.y, ca.y);
        ca.z = fmaf(a, eo.z, ca.z); ca.w = fmaf(a, eo.w, ca.w);
      }
      *(float4*)(&ctxp[sh][d4]) = ca;
    }
    __syncthreads();
    if (tid < 128) {
      int d = tid * 4;
#pragma unroll
      for (int i = 0; i < 4; ++i) {
        float v = ctxp[0][d + i] + ctxp[1][d + i] + ctxp[2][d + i] + ctxp[3][d + i];
        atomicAdd(ws + OFF_CTX + b1 * 512 + d + i, v);   // device-scope
      }
    }
    fbar(flags, g, 32, 3 * t + 2);

    // ---- P3: stage hcat=[ctx;h] to LDS, LSTM cell ----
    for (int e = tid; e < 6144; e += 512) {
      int bb = e / 768, kk2 = e % 768;
      hc_s[e] = (kk2 < 512) ? ald(ws + OFF_CTX + bb * 512 + kk2)
                            : ald(ws + OFF_HBUF + rb * 2048 + bb * 256 + (kk2 - 512));
    }
    __syncthreads();
    if (g < 8) ws[OFF_CS + ((size_t)t * 8 + g) * 512 + tid] = hc_s[g * 768 + tid];  // ctx for k_pgen
    {
      const float* hc  = &hc_s[b3 * 768];
      const float* wr1 = wih_d + (size_t)j * 768 + 256 + kc * 256;
      const float* hc1 = hc + kc * 256;
      float acc = 0.f;
#pragma unroll 8
      for (int kk = 0; kk < 256; kk += 4) {
        float4 wv = *(const float4*)(wr1 + kk);
        float4 hv = *(const float4*)(hc1 + kk);
        acc += wv.x * hv.x + wv.y * hv.y + wv.z * hv.z + wv.w * hv.w;
      }
      const float* wr2 = whh_d + (size_t)j * 256 + kc * 128;
      const float* hc2 = hc + 512 + kc * 128;
#pragma unroll 8
      for (int kk = 0; kk < 128; kk += 4) {
        float4 wv = *(const float4*)(wr2 + kk);
        float4 hv = *(const float4*)(hc2 + kk);
        acc += wv.x * hv.x + wv.y * hv.y + wv.z * hv.z + wv.w * hv.w;
      }
      acc += __shfl_xor(acc, 1);
      float z = ws[OFF_DPRE + ((size_t)t * 8 + b3) * 1024 + j] + acc;
      float y1 = __shfl_xor(z, 2), y2 = __shfl_xor(z, 4), y3 = __shfl_xor(z, 6);
      float zi = pick4(z, y1, y2, y3, gate);
      float zf = pick4(z, y1, y2, y3, gate ^ 1);
      float zg = pick4(z, y1, y2, y3, gate ^ 2);
      float zo = pick4(z, y1, y2, y3, gate ^ 3);
      float cn = sigf(zf) * c_reg + sigf(zi) * tanh_fast(zg);
      float hn = sigf(zo) * tanh_fast(cn);
      c_reg = cn;
      if (gate == 0 && kc == 0) {
        ast(ws + OFF_HBUF + wb * 2048 + b3 * 256 + u, hn);
        ws[OFF_HS + ((size_t)t * 8 + b3) * 256 + u] = hn;   // plain: post-kernel
      }
    }
    fbar(flags, g, 32, 3 * t + 3);
  }
}

__global__ __launch_bounds__(64) void k_pgen(const float* w_ptr, const float* b_ptr, float* ws) {
  int r = blockIdx.x, lane = threadIdx.x;
  float p = 0.f;
#pragma unroll
  for (int i = 0; i < 12; ++i) {
    int k = lane + 64 * i;
    float v = (k < 512) ? ws[OFF_CS + (size_t)r * 512 + k]
                        : ws[OFF_HS + (size_t)r * 256 + (k - 512)];
    p += v * w_ptr[k];
  }
#pragma unroll
  for (int m = 1; m < 64; m <<= 1) p += __shfl_xor(p, m);
  if (lane == 0) ws[OFF_PG + r] = sigf(p + b_ptr[0]);
}

// ---------------- fused vocab softmax + pointer scatter + CE loss (in-place on d_out) ----------------
__global__ __launch_bounds__(256) void k_v2(const int* xin, const int* labels, float* ws, float* out) {
  __shared__ float redm[256], reds[256];
  __shared__ int xv[200];
  __shared__ float s1sh, corrsh;
  int r = blockIdx.x, tid = threadIdx.x;
  int tt = r >> 3, b = r & 7;
  float* row = out + (size_t)(b * 50 + tt) * 64000;
  for (int i = tid; i < 200; i += 256) xv[i] = xin[b * 200 + i];
  float m = -1e30f, s = 0.f;
  for (int i = tid; i < 32000; i += 256) {
    float z = row[i];
    float nm = fmaxf(m, z);
    s = s * __expf(m - nm) + __expf(z - nm);
    m = nm;
  }
  redm[tid] = m; reds[tid] = s;
  __syncthreads();
  for (int st = 128; st >= 1; st >>= 1) {
    if (tid < st) {
      float m2 = redm[tid + st], s2 = reds[tid + st];
      float M = fmaxf(redm[tid], m2);
      reds[tid] = reds[tid] * __expf(redm[tid] - M) + s2 * __expf(m2 - M);
      redm[tid] = M;
    }
    __syncthreads();
  }
  float mx = redm[0], sum = reds[0];
  float pg = ws[OFF_PG + r];
  __syncthreads();
  float s1 = 0.f;
  float inv = 1.0f / sum;
  for (int i = tid; i < 32000; i += 256) {
    float z = row[i];
    float d = pg * (__expf(z - mx) * inv);
    row[i] = d;
    s1 += __expf(d);
  }
  for (int i = 32000 + tid; i < 64000; i += 256) row[i] = 0.0f;
  reds[tid] = s1;
  __syncthreads();
  for (int st = 128; st >= 1; st >>= 1) { if (tid < st) reds[tid] += reds[tid + st]; __syncthreads(); }
  if (tid == 0) { s1sh = reds[0]; corrsh = 0.f; }
  __syncthreads();
  if (tid < 200) {
    int v = xv[tid];
    bool own = true;
    for (int s2 = 0; s2 < tid; ++s2) if (xv[s2] == v) { own = false; break; }
    if (own) {
      float delta = 0.f;
      for (int s2 = tid; s2 < 200; ++s2)
        if (xv[s2] == v) delta += ws[OFF_AS + (size_t)r * 200 + s2];
      delta *= (1.0f - pg);
      float base = row[v];
      row[v] = base + delta;
      atomicAdd(&corrsh, __expf(base + delta) - __expf(base));
    }
  }
  __syncthreads();
  if (tid == 0) {
    float lse = logf(s1sh + corrsh + 32000.0f);
    int tgt = labels[b * 51 + tt + 1];
    float dt = row[tgt];
    float valid = (tgt != 0) ? 1.f : 0.f;
    atomicAdd(ws + OFF_ACC + 0, valid * (lse - dt));
    atomicAdd(ws + OFF_ACC + 1, valid);
  }
}

__global__ void k_loss(float* ws, float* out, int out_size) {
  out[out_size - 1] = ws[OFF_ACC + 0] / ws[OFF_ACC + 1] + ws[OFF_ACC + 2] / ws[OFF_ACC + 3];
}

// ---------------- launch ----------------
extern "C" void kernel_launch(void* const* d_in, const int* in_sizes, int n_in,
                              void* d_out, int out_size, void* d_ws, size_t ws_size,
                              hipStream_t stream) {
  (void)in_sizes; (void)n_in; (void)ws_size;
  const int*   x       = (const int*)  d_in[0];
  const int*   labels  = (const int*)  d_in[1];
  const float* emb_enc = (const float*)d_in[3];
  const float* wih_f   = (const float*)d_in[4];
  const float* whh_f   = (const float*)d_in[5];
  const float* bih_f   = (const float*)d_in[6];
  const float* bhh_f   = (const float*)d_in[7];
  const float* wih_b   = (const float*)d_in[8];
  const float* whh_b   = (const float*)d_in[9];
  const float* bih_b   = (const float*)d_in[10];
  const float* bhh_b   = (const float*)d_in[11];
  const float* w_sel1  = (const float*)d_in[12];
  const float* b_sel1  = (const float*)d_in[13];
  const float* w_sel2  = (const float*)d_in[14];
  const float* b_sel2  = (const float*)d_in[15];
  const float* w_rh    = (const float*)d_in[16];
  const float* b_rh    = (const float*)d_in[17];
  const float* w_rc    = (const float*)d_in[18];
  const float* b_rc    = (const float*)d_in[19];
  const float* emb_dec = (const float*)d_in[20];
  const float* wih_d   = (const float*)d_in[21];
  const float* whh_d   = (const float*)d_in[22];
  const float* bih_d   = (const float*)d_in[23];
  const float* bhh_d   = (const float*)d_in[24];
  const float* w_attn  = (const float*)d_in[25];
  const float* b_attn  = (const float*)d_in[26];
  const float* w_attn_v= (const float*)d_in[27];
  const float* w_ptr   = (const float*)d_in[28];
  const float* b_ptr   = (const float*)d_in[29];
  const float* w_gen   = (const float*)d_in[30];
  const float* b_gen   = (const float*)d_in[31];
  const float* w_cov   = (const float*)d_in[32];
  const float* b_cov   = (const float*)d_in[33];
  float* ws  = (float*)d_ws;
  float* out = (float*)d_out;

  hipMemsetAsync(d_ws, 0, ZERO_FLOATS * 4, stream);
  k_biassum<<<12, 256, 0, stream>>>(bih_f, bhh_f, bih_b, bhh_b, bih_d, bhh_d, ws);
  k_embed<<<2000, 256, 0, stream>>>(x, labels, emb_enc, emb_dec, ws);
  k_gemm<64,64,4,4,0,0,0><<<dim3(25,16), 256, 0, stream>>>(ws+OFF_EMB,  wih_f, ws+OFF_BIAS,      ws+OFF_PREF, 1600, 256, 256, 1024);
  k_gemm<64,64,4,4,0,0,1><<<dim3(25,16), 256, 0, stream>>>(ws+OFF_EMB,  wih_b, ws+OFF_BIAS+1024, ws+OFF_PREB, 1600, 256, 256, 1024);
  k_gemm<64,64,4,4,0,0,0><<<dim3(7,16),  256, 0, stream>>>(ws+OFF_DEMB, wih_d, ws+OFF_BIAS+2048, ws+OFF_DPRE, 400,  256, 768, 1024);
  k_encoder<<<32, 512, 0, stream>>>(whh_f, whh_b, ws);
  k_gemm<64,64,4,4,0,1,0><<<dim3(25,4),  256, 0, stream>>>(ws+OFF_ENCOUT, w_sel1, b_sel1, ws+OFF_HSEL, 1600, 512, 512, 256);
  k_selbce<<<1600, 64, 0, stream>>>(w_sel2, b_sel2, x, ws);
  k_gemm<64,64,4,4,0,0,0><<<dim3(25,4),  256, 0, stream>>>(ws+OFF_ENCOUT, w_attn, b_attn, ws+OFF_EP, 1600, 512, 1024, 256);
  k_wcp<<<1, 256, 0, stream>>>(w_attn, w_cov, b_cov, ws);
  k_wat<<<256, 256, 0, stream>>>(w_attn, ws);
  k_h0c0<<<8, 256, 0, stream>>>(w_rh, b_rh, w_rc, b_rc, ws);
  k_decoder<<<32, 512, 0, stream>>>(wih_d, whh_d, w_attn_v, ws);
  k_pgen<<<400, 64, 0, stream>>>(w_ptr, b_ptr, ws);
  k_gemm<128,128,8,8,1,0,0><<<dim3(4,250), 256, 0, stream>>>(ws+OFF_HS, w_gen, b_gen, out, 400, 256, 256, 64000);
  k_v2<<<400, 256, 0, stream>>>(x, labels, ws, out);
  k_loss<<<1, 1, 0, stream>>>(ws, out, out_size);
}

// Round 3
// 2609.388 us; speedup vs baseline: 3.0951x; 1.4694x over previous
//
#include <hip/hip_runtime.h>
#include <hip/hip_bf16.h>
#include <stdint.h>

// B=8, S=200, H=256, V=32000, T=51. out = (8,50,64000) fp32 + scalar loss.

#define DEVI __device__ __forceinline__
#define AT_RLX __ATOMIC_RELAXED
#define SC_AGT __HIP_MEMORY_SCOPE_AGENT

// ---------------- ws layout (float offsets) ----------------
static constexpr size_t OFF_ACC   = 0;        // 4: nll_sum, valid_sum, bce_sum, m_sum
static constexpr size_t OFF_FLAGE = 4;        // 32 ints (encoder flags, 16/dir)
static constexpr size_t OFF_FLAGD = 36;       // 32 ints (decoder flags)
static constexpr size_t OFF_STAT  = 68;       // 32*4 softmax stats
static constexpr size_t ZERO_FLOATS = 200;
static constexpr size_t OFF_CTX   = 256;      // 8*512 ctx accumulators
static constexpr size_t OFF_EMB   = 4352;     // [t][b][h] 200*8*256 (reused as HSEL)
static constexpr size_t OFF_HSEL  = OFF_EMB;
static constexpr size_t OFF_PREF  = OFF_EMB  + 409600;
static constexpr size_t OFF_PREB  = OFF_PREF + 1638400;
static constexpr size_t OFF_BIAS  = OFF_PREB + 1638400;  // 3072
static constexpr size_t OFF_HB    = OFF_BIAS + 3072;     // enc h dbl buf 8192
static constexpr size_t OFF_HFIN  = OFF_HB   + 8192;     // 4096
static constexpr size_t OFF_CFIN  = OFF_HFIN + 4096;     // 4096
static constexpr size_t OFF_ENCOUT= OFF_CFIN + 4096;     // [b][s][512] = 819200
static constexpr size_t OFF_MASK  = OFF_ENCOUT + 819200; // 1600
static constexpr size_t OFF_C0    = OFF_MASK + 1600;     // 2048
static constexpr size_t OFF_EP    = OFF_C0   + 2048;     // [b][s][256] = 409600
static constexpr size_t OFF_WCP   = OFF_EP   + 409600;   // 256
static constexpr size_t OFF_BCP   = OFF_WCP  + 256;      // 256
static constexpr size_t OFF_DEMB  = OFF_BCP  + 256;      // 102400
static constexpr size_t OFF_DPRE  = OFF_DEMB + 102400;   // 409600
static constexpr size_t OFF_HBUF  = OFF_DPRE + 409600;   // dec h dbl buf 4096
static constexpr size_t OFF_CS    = OFF_HBUF + 4096;     // 204800
static constexpr size_t OFF_HS    = OFF_CS   + 204800;   // 102400
static constexpr size_t OFF_AS    = OFF_HS   + 102400;   // 80000
static constexpr size_t OFF_PG    = OFF_AS   + 80000;    // 400 (pad 512)
static constexpr size_t OFF_HW    = OFF_PG   + 512;      // hW dbl buf [2][8][256] = 4096

// ---------------- helpers ----------------
DEVI float sigf(float x)      { return 1.0f / (1.0f + __expf(-x)); }
DEVI float tanh_fast(float x) { return 1.0f - 2.0f / (1.0f + __expf(2.0f * x)); }
DEVI float pick4(float z, float x1, float x2, float x3, int mm) {
  return mm == 0 ? z : (mm == 1 ? x1 : (mm == 2 ? x2 : x3));
}
DEVI float ald(const float* p)  { return __hip_atomic_load((float*)p, AT_RLX, SC_AGT); }
DEVI void  ast(float* p, float v){ __hip_atomic_store(p, v, AT_RLX, SC_AGT); }

// Distributed flag barrier, RELAXED flag store: __syncthreads() already drains
// vmcnt(0) per wave, so all prior agent-scope atomic stores have completed at
// the coherence point; no release (no buffer_wbl2 L2 flush) needed.
DEVI void fbar(int* flags, int g, int n, int val) {
  __syncthreads();
  if ((int)threadIdx.x == 0)
    __hip_atomic_store(flags + g, val, AT_RLX, SC_AGT);
  if ((int)threadIdx.x < n && (int)threadIdx.x != g) {
    while (__hip_atomic_load(flags + threadIdx.x, AT_RLX, SC_AGT) < val)
      __builtin_amdgcn_s_sleep(2);
  }
  __syncthreads();
}

// ---------------- small prep kernels ----------------
__global__ __launch_bounds__(256) void k_biassum(
    const float* bih_f, const float* bhh_f, const float* bih_b, const float* bhh_b,
    const float* bih_d, const float* bhh_d, float* ws) {
  int i = blockIdx.x * 256 + threadIdx.x;
  int which = i >> 10, jj = i & 1023;
  float v = (which == 0) ? bih_f[jj] + bhh_f[jj]
          : (which == 1) ? bih_b[jj] + bhh_b[jj]
                         : bih_d[jj] + bhh_d[jj];
  ws[OFF_BIAS + i] = v;
}

__global__ __launch_bounds__(256) void k_embed(
    const int* xin, const int* labels, const float* emb_enc, const float* emb_dec, float* ws) {
  int r = blockIdx.x, h = threadIdx.x;
  if (r < 1600) {
    int t = r >> 3, b = r & 7;
    ws[OFF_EMB + (size_t)r * 256 + h] = emb_enc[(size_t)xin[b * 200 + t] * 256 + h];
  } else {
    int r2 = r - 1600;
    int t = r2 >> 3, b = r2 & 7;
    int tok = (t == 0) ? 1 : labels[b * 51 + t];
    ws[OFF_DEMB + (size_t)r2 * 256 + h] = emb_dec[(size_t)tok * 256 + h];
  }
}

// ---------------- tiled SGEMM: C[m][n] = act(sum_k A[m][k]*B[n][k] + bias[n]) ----------------
template<int BM, int BN, int TM, int TN, int CMAP, int ACT, int AMAP>
__global__ __launch_bounds__(256) void k_gemm(
    const float* __restrict__ A, const float* __restrict__ B,
    const float* __restrict__ bias, float* __restrict__ C,
    int M, int K, int ldb, int ldc) {
  __shared__ float As[16][BM];
  __shared__ float Bs[16][BN];
  const int tid = threadIdx.x;
  const int tx = tid & 15, ty = tid >> 4;
  const int m0 = blockIdx.x * BM, n0 = blockIdx.y * BN;
  float acc[TM][TN];
#pragma unroll
  for (int i = 0; i < TM; ++i)
#pragma unroll
    for (int q = 0; q < TN; ++q) acc[i][q] = 0.f;

  for (int kk = 0; kk < K; kk += 16) {
#pragma unroll
    for (int e = tid; e < BM * 4; e += 256) {
      int m = e >> 2, k4 = (e & 3) * 4;
      int gm0 = m0 + m;
      float4 v = {0.f, 0.f, 0.f, 0.f};
      if (gm0 < M) {
        int gm = AMAP ? (((199 - (gm0 >> 3)) << 3) + (gm0 & 7)) : gm0;
        v = *(const float4*)(A + (size_t)gm * K + kk + k4);
      }
      As[k4 + 0][m] = v.x; As[k4 + 1][m] = v.y; As[k4 + 2][m] = v.z; As[k4 + 3][m] = v.w;
    }
#pragma unroll
    for (int e = tid; e < BN * 4; e += 256) {
      int n = e >> 2, k4 = (e & 3) * 4;
      float4 v = *(const float4*)(B + (size_t)(n0 + n) * ldb + kk + k4);
      Bs[k4 + 0][n] = v.x; Bs[k4 + 1][n] = v.y; Bs[k4 + 2][n] = v.z; Bs[k4 + 3][n] = v.w;
    }
    __syncthreads();
#pragma unroll
    for (int k = 0; k < 16; ++k) {
      float a[TM], bv[TN];
#pragma unroll
      for (int i = 0; i < TM; ++i) a[i] = As[k][ty * TM + i];
#pragma unroll
      for (int q = 0; q < TN; ++q) bv[q] = Bs[k][tx * TN + q];
#pragma unroll
      for (int i = 0; i < TM; ++i)
#pragma unroll
        for (int q = 0; q < TN; ++q) acc[i][q] += a[i] * bv[q];
    }
    __syncthreads();
  }
#pragma unroll
  for (int i = 0; i < TM; ++i) {
    int gm = m0 + ty * TM + i;
    if (gm >= M) continue;
    size_t base;
    if (CMAP == 1) { int t = gm >> 3, b = gm & 7; base = (size_t)(b * 50 + t) * 64000; }
    else            base = (size_t)gm * ldc;
#pragma unroll
    for (int q = 0; q < TN; ++q) {
      int n = n0 + tx * TN + q;
      float v = acc[i][q] + bias[n];
      if (ACT == 1) v = tanh_fast(v);
      C[base + n] = v;
    }
  }
}

// ---------------- encoder: 32 blocks (16/dir), weights in registers ----------------
__global__ __launch_bounds__(512, 1) void k_encoder(
    const float* __restrict__ whh_f, const float* __restrict__ whh_b, float* __restrict__ ws) {
  __shared__ float hs[8 * 288];
  __shared__ float zs[512];
  const int dir = blockIdx.x >> 4;
  const int p   = blockIdx.x & 15;
  const int u0  = p * 16;
  const float* whh = dir ? whh_b : whh_f;
  const float* pre = ws + (dir ? OFF_PREB : OFF_PREF);
  int* flags = (int*)(ws + OFF_FLAGE) + dir * 16;
  const int tid = threadIdx.x;
  const int r = tid >> 3, kc = tid & 7;
  const int gt = r >> 4, ui = r & 15;
  const int j = gt * 256 + u0 + ui;
  float4 W[8];
  {
    const float* wr = whh + (size_t)j * 256 + kc * 32;
#pragma unroll
    for (int q = 0; q < 8; ++q) W[q] = *(const float4*)(wr + q * 4);
  }
  const int ui2 = tid & 15, b2 = tid >> 4;
  float c_reg = 0.f;
  float* hBa = ws + OFF_HB;
  float* enc = ws + OFF_ENCOUT;

  for (int t = 0; t < 200; ++t) {
    float pre_v = pre[((size_t)t * 8 + kc) * 1024 + j];
    float acc[8];
#pragma unroll
    for (int b = 0; b < 8; ++b) acc[b] = 0.f;
    if (t > 0) {
      {
        float* src = hBa + (size_t)((((t + 1) & 1) * 2 + dir) * 2048) + tid * 4;
        float v0 = ald(src + 0);
        float v1 = ald(src + 1);
        float v2 = ald(src + 2);
        float v3 = ald(src + 3);
        int kk0 = (tid * 4) & 255, bb = tid >> 6;
        float* dst = &hs[bb * 288 + (kk0 >> 5) * 36 + (kk0 & 31)];
        dst[0] = v0; dst[1] = v1; dst[2] = v2; dst[3] = v3;
      }
      __syncthreads();
      const float* hrow = &hs[kc * 36];
#pragma unroll
      for (int b = 0; b < 8; ++b) {
        const float* hbp = hrow + b * 288;
#pragma unroll
        for (int q = 0; q < 8; ++q) {
          float4 h4 = *(const float4*)(hbp + q * 4);
          acc[b] = fmaf(W[q].x, h4.x, acc[b]);
          acc[b] = fmaf(W[q].y, h4.y, acc[b]);
          acc[b] = fmaf(W[q].z, h4.z, acc[b]);
          acc[b] = fmaf(W[q].w, h4.w, acc[b]);
        }
      }
    }
    {
      bool h4b = (kc & 4) != 0;
#pragma unroll
      for (int i = 0; i < 4; ++i) {
        float send = h4b ? acc[i] : acc[i + 4];
        float keep = h4b ? acc[i + 4] : acc[i];
        acc[i] = keep + __shfl_xor(send, 4);
      }
      bool h2b = (kc & 2) != 0;
#pragma unroll
      for (int i = 0; i < 2; ++i) {
        float send = h2b ? acc[i] : acc[i + 2];
        float keep = h2b ? acc[i + 2] : acc[i];
        acc[i] = keep + __shfl_xor(send, 2);
      }
      bool h1b = (kc & 1) != 0;
      {
        float send = h1b ? acc[0] : acc[1];
        float keep = h1b ? acc[1] : acc[0];
        acc[0] = keep + __shfl_xor(send, 1);
      }
    }
    zs[tid] = acc[0] + pre_v;
    __syncthreads();
    if (tid < 128) {
      int i0 = ui2 * 8 + b2;
      float zi = zs[i0], zf = zs[128 + i0], zg = zs[256 + i0], zo = zs[384 + i0];
      float cn = sigf(zf) * c_reg + sigf(zi) * tanh_fast(zg);
      float hn = sigf(zo) * tanh_fast(cn);
      c_reg = cn;
      int uu = u0 + ui2;
      ast(hBa + (size_t)(((t & 1) * 2 + dir) * 2048) + b2 * 256 + uu, hn);
      int s = dir ? (199 - t) : t;
      enc[((size_t)b2 * 200 + s) * 512 + dir * 256 + uu] = hn;
      if (t == 199) {
        ws[OFF_HFIN + (size_t)(dir * 8 + b2) * 256 + uu] = hn;
        ws[OFF_CFIN + (size_t)(dir * 8 + b2) * 256 + uu] = cn;
      }
    }
    if (t < 199) fbar(flags, p, 16, t + 1);
  }
}

// ---------------- copy-prob head + BCE ----------------
__global__ __launch_bounds__(64) void k_selbce(
    const float* w_sel2, const float* b_sel2, const int* xin, float* ws) {
  int r = blockIdx.x, lane = threadIdx.x;
  float pacc = 0.f;
#pragma unroll
  for (int i = 0; i < 4; ++i) {
    int k = lane + 64 * i;
    pacc += ws[OFF_HSEL + (size_t)r * 256 + k] * w_sel2[k];
  }
#pragma unroll
  for (int m = 1; m < 64; m <<= 1) pacc += __shfl_xor(pacc, m);
  if (lane == 0) {
    float cp = sigf(pacc + b_sel2[0]);
    ws[OFF_MASK + r] = (cp > 1e-8f) ? 1.f : 0.f;
    int b = r / 200, s = r % 200;
    float m = (xin[b * 200 + s] != 0) ? 1.f : 0.f;
    if (m > 0.f) {
      float lp = fmaxf(logf(cp), -100.f);
      atomicAdd(ws + OFF_ACC + 2, -lp);
    }
    atomicAdd(ws + OFF_ACC + 3, m);
  }
}

__global__ __launch_bounds__(256) void k_wcp(
    const float* w_attn, const float* w_cov, const float* b_cov, float* ws) {
  int jj = threadIdx.x;
  float a = 0.f, c = 0.f;
  for (int h = 0; h < 256; ++h) {
    float w = w_attn[(size_t)jj * 1024 + 768 + h];
    a += w * w_cov[h];
    c += w * b_cov[h];
  }
  ws[OFF_WCP + jj] = a;
  ws[OFF_BCP + jj] = c;
}

__global__ __launch_bounds__(256) void k_h0c0(
    const float* w_rh, const float* b_rh, const float* w_rc, const float* b_rc, float* ws) {
  int b = blockIdx.x, jj = threadIdx.x;
  const float* hf  = ws + OFF_HFIN + (size_t)b * 256;
  const float* hbk = ws + OFF_HFIN + 2048 + (size_t)b * 256;
  const float* cf  = ws + OFF_CFIN + (size_t)b * 256;
  const float* cbk = ws + OFF_CFIN + 2048 + (size_t)b * 256;
  float ah = b_rh[jj], ac = b_rc[jj];
  for (int k = 0; k < 256; ++k) {
    ah += hf[k] * w_rh[(size_t)jj * 512 + k];
    ac += cf[k] * w_rc[(size_t)jj * 512 + k];
  }
  for (int k = 0; k < 256; ++k) {
    ah += hbk[k] * w_rh[(size_t)jj * 512 + 256 + k];
    ac += cbk[k] * w_rc[(size_t)jj * 512 + 256 + k];
  }
  ws[OFF_C0 + (size_t)b * 256 + jj] = fmaxf(ac, 0.f);
  ws[OFF_HBUF + (size_t)b * 256 + jj] = fmaxf(ah, 0.f);
}

// hW(t=0) = h0 @ waT into buf0; zero buf1.
__global__ __launch_bounds__(256) void k_hw0(const float* w_attn, float* ws) {
  __shared__ float h0s[256];
  int b = blockIdx.x, jj = threadIdx.x;
  h0s[jj] = ws[OFF_HBUF + (size_t)b * 256 + jj];
  __syncthreads();
  float a = 0.f;
  const float* wr = w_attn + (size_t)jj * 1024 + 512;
  for (int k = 0; k < 256; k += 4) {
    float4 w4 = *(const float4*)(wr + k);
    a = fmaf(h0s[k], w4.x, a); a = fmaf(h0s[k + 1], w4.y, a);
    a = fmaf(h0s[k + 2], w4.z, a); a = fmaf(h0s[k + 3], w4.w, a);
  }
  ws[OFF_HW + (size_t)b * 256 + jj] = a;
  ws[OFF_HW + 2048 + (size_t)b * 256 + jj] = 0.f;
}

// ---------------- decoder: 32 blocks, 3 relaxed barriers/step, reg-resident weights ----------------
__global__ __launch_bounds__(512, 1) void k_decoder(
    const float* __restrict__ wih_d, const float* __restrict__ whh_d,
    const float* __restrict__ w_attn, const float* __restrict__ w_attn_v,
    float* __restrict__ ws) {
  __shared__ float hc_s[8 * 768];     // [b][ctx512 | h256]
  __shared__ float hw_s[256];
  __shared__ float zs_l[256];         // z at [row_l][b]
  __shared__ float h_s[64];           // h at [u_l][b]
  __shared__ float sc_s[64], msk_s[64], cv_s[64], at_s[64];
  __shared__ float st_s[12], mS_s[2];
  __shared__ float ctxp[4][512];
  const int g = blockIdx.x, tid = threadIdx.x;
  const int lane = tid & 63, w1 = tid >> 6;
  const int b1 = g >> 2, sq = g & 3, s0 = sq * 50;
  int* flags = (int*)(ws + OFF_FLAGD);
  float* hwb = ws + OFF_HW;           // [2][8][256]
  // ---- P3 roles: kseg in [0,16), row_l in [0,32) ----
  const int kseg = tid & 15, row_l = tid >> 4;
  const int u_l = row_l & 7, gate = row_l >> 3;
  const int j = gate * 256 + g * 8 + u_l;
  // LSTM weights (K'=768 = [ctx 512][h 256]), k = 4*kseg + 64*q, 12 float4/thread.
  float4 W48[12];
#pragma unroll
  for (int q = 0; q < 12; ++q) {
    int k0 = 4 * kseg + 64 * q;
    W48[q] = (k0 < 512) ? *(const float4*)(wih_d + (size_t)j * 768 + 256 + k0)
                        : *(const float4*)(whh_d + (size_t)j * 256 + (k0 - 512));
  }
  // hW-partial weights: W8r[i][c] = w_attn[jj0+c][512 + g*8 + i]
  float W8r[8][4];
  {
    int jj0 = (tid & 63) * 4;
#pragma unroll
    for (int i = 0; i < 8; ++i)
#pragma unroll
      for (int c = 0; c < 4; ++c)
        W8r[i][c] = w_attn[(size_t)(jj0 + c) * 1024 + 512 + g * 8 + i];
  }
  const int jb4 = lane * 4;
  float4 wcp4 = *(const float4*)(ws + OFF_WCP + jb4);
  float4 bcp4 = *(const float4*)(ws + OFF_BCP + jb4);
  float4 wav4 = *(const float4*)(w_attn_v + jb4);
  // cell-state role: tid<64 -> (b_c, u_c)
  const int u_c = tid & 7, b_c = tid >> 3;
  float c_reg = (tid < 64) ? ws[OFF_C0 + (size_t)b_c * 256 + g * 8 + u_c] : 0.f;
  if (tid < 64) {
    msk_s[tid] = (tid < 50) ? ws[OFF_MASK + b1 * 200 + s0 + tid] : 0.f;
    cv_s[tid] = 0.f;
  }
  __syncthreads();

  for (int t = 0; t < 50; ++t) {
    const int rb = t & 1, wb = 1 - rb;
    // ---- P1: zero ctx slice, read hW, scores, local softmax stats ----
    if (tid < 128) ast(ws + OFF_CTX + g * 128 + tid, 0.f);
    if (tid < 256) hw_s[tid] = ald(hwb + (size_t)rb * 2048 + b1 * 256 + tid);
    __syncthreads();
    for (int s = w1; s < 50; s += 8) {
      float cv = cv_s[s];
      float4 e4 = *(const float4*)(ws + OFF_EP + ((size_t)(b1 * 200 + s0 + s)) * 256 + jb4);
      float4 h4 = *(const float4*)(&hw_s[jb4]);
      float t0 = tanh_fast(e4.x + h4.x + cv * wcp4.x + bcp4.x);
      float t1 = tanh_fast(e4.y + h4.y + cv * wcp4.y + bcp4.y);
      float t2 = tanh_fast(e4.z + h4.z + cv * wcp4.z + bcp4.z);
      float t3 = tanh_fast(e4.w + h4.w + cv * wcp4.w + bcp4.w);
      float pp = t0 * wav4.x + t1 * wav4.y + t2 * wav4.z + t3 * wav4.w;
#pragma unroll
      for (int md = 1; md < 64; md <<= 1) pp += __shfl_xor(pp, md);
      if (lane == 0) sc_s[s] = pp;
    }
    __syncthreads();
    if (tid < 64) {
      float v = (tid < 50) ? sc_s[tid] : -1e30f;
      float mx = v;
#pragma unroll
      for (int m = 1; m < 64; m <<= 1) mx = fmaxf(mx, __shfl_xor(mx, m));
      float e = (tid < 50) ? __expf(v - mx) : 0.f;
      float es = e, ems = e * msk_s[tid];
#pragma unroll
      for (int m = 1; m < 64; m <<= 1) { es += __shfl_xor(es, m); ems += __shfl_xor(ems, m); }
      if (tid == 0) {
        ast(ws + OFF_STAT + g * 4 + 0, mx);
        ast(ws + OFF_STAT + g * 4 + 1, es);
        ast(ws + OFF_STAT + g * 4 + 2, ems);
      }
    }
    fbar(flags, g, 32, 3 * t + 1);

    // ---- P2: combine stats, attn, coverage, ctx partial; zero hW[rb] slice ----
    if (tid < 12) st_s[tid] = ald(ws + OFF_STAT + (size_t)(b1 * 4 + tid / 3) * 4 + tid % 3);
    if (tid >= 448) ast(hwb + (size_t)rb * 2048 + g * 64 + (tid - 448), 0.f);
    __syncthreads();
    if (tid == 0) {
      float m = fmaxf(fmaxf(st_s[0], st_s[3]), fmaxf(st_s[6], st_s[9]));
      float e0 = __expf(st_s[0] - m), e1 = __expf(st_s[3] - m), e2 = __expf(st_s[6] - m), e3 = __expf(st_s[9] - m);
      float S  = st_s[1] * e0 + st_s[4] * e1 + st_s[7] * e2 + st_s[10] * e3;
      float MS = st_s[2] * e0 + st_s[5] * e1 + st_s[8] * e2 + st_s[11] * e3;
      mS_s[0] = m; mS_s[1] = 1.0f / (MS + 1e-10f * S);
    }
    __syncthreads();
    if (tid < 50) {
      float a = __expf(sc_s[tid] - mS_s[0]) * msk_s[tid] * mS_s[1];
      at_s[tid] = a;
      cv_s[tid] += a;
      ws[OFF_AS + ((size_t)t * 8 + b1) * 200 + s0 + tid] = a;
    }
    __syncthreads();
    {
      int d4 = (tid & 127) * 4, sh = tid >> 7;
      float4 ca = {0.f, 0.f, 0.f, 0.f};
      for (int s = sh; s < 50; s += 4) {
        float a = at_s[s];
        float4 eo = *(const float4*)(ws + OFF_ENCOUT + ((size_t)(b1 * 200 + s0 + s)) * 512 + d4);
        ca.x = fmaf(a, eo.x, ca.x); ca.y = fmaf(a, eo.y, ca.y);
        ca.z = fmaf(a, eo.z, ca.z); ca.w = fmaf(a, eo.w, ca.w);
      }
      *(float4*)(&ctxp[sh][d4]) = ca;
    }
    __syncthreads();
    if (tid < 128) {
      int d = tid * 4;
#pragma unroll
      for (int i = 0; i < 4; ++i) {
        float v = ctxp[0][d + i] + ctxp[1][d + i] + ctxp[2][d + i] + ctxp[3][d + i];
        atomicAdd(ws + OFF_CTX + b1 * 512 + d + i, v);
      }
    }
    fbar(flags, g, 32, 3 * t + 2);

    // ---- P3: stage hcat, LSTM cell (reg weights), hW partial accumulate ----
    for (int e = tid; e < 6144; e += 512) {
      int bb = e / 768, kk2 = e % 768;
      hc_s[e] = (kk2 < 512) ? ald(ws + OFF_CTX + bb * 512 + kk2)
                            : ald(ws + OFF_HBUF + (size_t)rb * 2048 + bb * 256 + (kk2 - 512));
    }
    __syncthreads();
    if (g < 8) ws[OFF_CS + ((size_t)t * 8 + g) * 512 + tid] = hc_s[g * 768 + tid];
    float acc[8];
#pragma unroll
    for (int b = 0; b < 8; ++b) acc[b] = 0.f;
#pragma unroll
    for (int q = 0; q < 12; ++q) {
      int k0 = 4 * kseg + 64 * q;
#pragma unroll
      for (int b = 0; b < 8; ++b) {
        float4 h4 = *(const float4*)(&hc_s[b * 768 + k0]);
        acc[b] = fmaf(W48[q].x, h4.x, acc[b]);
        acc[b] = fmaf(W48[q].y, h4.y, acc[b]);
        acc[b] = fmaf(W48[q].z, h4.z, acc[b]);
        acc[b] = fmaf(W48[q].w, h4.w, acc[b]);
      }
    }
    // reduce-scatter over 16 ksegs -> lane holds z for b = kseg>>1
    {
      bool h8 = (kseg & 8) != 0;
#pragma unroll
      for (int i = 0; i < 4; ++i) {
        float send = h8 ? acc[i] : acc[i + 4];
        float keep = h8 ? acc[i + 4] : acc[i];
        acc[i] = keep + __shfl_xor(send, 8);
      }
      bool h4b = (kseg & 4) != 0;
#pragma unroll
      for (int i = 0; i < 2; ++i) {
        float send = h4b ? acc[i] : acc[i + 2];
        float keep = h4b ? acc[i + 2] : acc[i];
        acc[i] = keep + __shfl_xor(send, 4);
      }
      bool h2b = (kseg & 2) != 0;
      {
        float send = h2b ? acc[0] : acc[1];
        float keep = h2b ? acc[1] : acc[0];
        acc[0] = keep + __shfl_xor(send, 2);
      }
      acc[0] += __shfl_xor(acc[0], 1);
    }
    {
      int bz = kseg >> 1;
      float z = acc[0] + ws[OFF_DPRE + ((size_t)t * 8 + bz) * 1024 + j];
      if ((kseg & 1) == 0) zs_l[row_l * 8 + bz] = z;
    }
    __syncthreads();
    if (tid < 64) {
      float zi = zs_l[(0  + u_c) * 8 + b_c];
      float zf = zs_l[(8  + u_c) * 8 + b_c];
      float zg = zs_l[(16 + u_c) * 8 + b_c];
      float zo = zs_l[(24 + u_c) * 8 + b_c];
      float cn = sigf(zf) * c_reg + sigf(zi) * tanh_fast(zg);
      float hn = sigf(zo) * tanh_fast(cn);
      c_reg = cn;
      ast(ws + OFF_HBUF + (size_t)wb * 2048 + b_c * 256 + g * 8 + u_c, hn);
      ws[OFF_HS + ((size_t)t * 8 + b_c) * 256 + g * 8 + u_c] = hn;
      h_s[u_c * 8 + b_c] = hn;
    }
    __syncthreads();
    {
      int bh = tid >> 6, jj0 = (tid & 63) * 4;
      float a0 = 0.f, a1 = 0.f, a2 = 0.f, a3 = 0.f;
#pragma unroll
      for (int i = 0; i < 8; ++i) {
        float hv = h_s[i * 8 + bh];
        a0 = fmaf(hv, W8r[i][0], a0);
        a1 = fmaf(hv, W8r[i][1], a1);
        a2 = fmaf(hv, W8r[i][2], a2);
        a3 = fmaf(hv, W8r[i][3], a3);
      }
      float* dst = hwb + (size_t)wb * 2048 + bh * 256 + jj0;
      atomicAdd(dst + 0, a0);
      atomicAdd(dst + 1, a1);
      atomicAdd(dst + 2, a2);
      atomicAdd(dst + 3, a3);
    }
    fbar(flags, g, 32, 3 * t + 3);
  }
}

__global__ __launch_bounds__(64) void k_pgen(const float* w_ptr, const float* b_ptr, float* ws) {
  int r = blockIdx.x, lane = threadIdx.x;
  float p = 0.f;
#pragma unroll
  for (int i = 0; i < 12; ++i) {
    int k = lane + 64 * i;
    float v = (k < 512) ? ws[OFF_CS + (size_t)r * 512 + k]
                        : ws[OFF_HS + (size_t)r * 256 + (k - 512)];
    p += v * w_ptr[k];
  }
#pragma unroll
  for (int m = 1; m < 64; m <<= 1) p += __shfl_xor(p, m);
  if (lane == 0) ws[OFF_PG + r] = sigf(p + b_ptr[0]);
}

// ---------------- fused vocab softmax + pointer scatter + CE loss ----------------
__global__ __launch_bounds__(256) void k_v2(const int* xin, const int* labels, float* ws, float* out) {
  __shared__ float redm[256], reds[256];
  __shared__ int xv[200];
  __shared__ float s1sh, corrsh;
  int r = blockIdx.x, tid = threadIdx.x;
  int tt = r >> 3, b = r & 7;
  float* row = out + (size_t)(b * 50 + tt) * 64000;
  for (int i = tid; i < 200; i += 256) xv[i] = xin[b * 200 + i];
  float m = -1e30f, s = 0.f;
  for (int i = tid; i < 32000; i += 256) {
    float z = row[i];
    float nm = fmaxf(m, z);
    s = s * __expf(m - nm) + __expf(z - nm);
    m = nm;
  }
  redm[tid] = m; reds[tid] = s;
  __syncthreads();
  for (int st = 128; st >= 1; st >>= 1) {
    if (tid < st) {
      float m2 = redm[tid + st], s2 = reds[tid + st];
      float M = fmaxf(redm[tid], m2);
      reds[tid] = reds[tid] * __expf(redm[tid] - M) + s2 * __expf(m2 - M);
      redm[tid] = M;
    }
    __syncthreads();
  }
  float mx = redm[0], sum = reds[0];
  float pg = ws[OFF_PG + r];
  __syncthreads();
  float s1 = 0.f;
  float inv = 1.0f / sum;
  for (int i = tid; i < 32000; i += 256) {
    float z = row[i];
    float d = pg * (__expf(z - mx) * inv);
    row[i] = d;
    s1 += __expf(d);
  }
  for (int i = 32000 + tid; i < 64000; i += 256) row[i] = 0.0f;
  reds[tid] = s1;
  __syncthreads();
  for (int st = 128; st >= 1; st >>= 1) { if (tid < st) reds[tid] += reds[tid + st]; __syncthreads(); }
  if (tid == 0) { s1sh = reds[0]; corrsh = 0.f; }
  __syncthreads();
  if (tid < 200) {
    int v = xv[tid];
    bool own = true;
    for (int s2 = 0; s2 < tid; ++s2) if (xv[s2] == v) { own = false; break; }
    if (own) {
      float delta = 0.f;
      for (int s2 = tid; s2 < 200; ++s2)
        if (xv[s2] == v) delta += ws[OFF_AS + (size_t)r * 200 + s2];
      delta *= (1.0f - pg);
      float base = row[v];
      row[v] = base + delta;
      atomicAdd(&corrsh, __expf(base + delta) - __expf(base));
    }
  }
  __syncthreads();
  if (tid == 0) {
    float lse = logf(s1sh + corrsh + 32000.0f);
    int tgt = labels[b * 51 + tt + 1];
    float dt = row[tgt];
    float valid = (tgt != 0) ? 1.f : 0.f;
    atomicAdd(ws + OFF_ACC + 0, valid * (lse - dt));
    atomicAdd(ws + OFF_ACC + 1, valid);
  }
}

__global__ void k_loss(float* ws, float* out, int out_size) {
  out[out_size - 1] = ws[OFF_ACC + 0] / ws[OFF_ACC + 1] + ws[OFF_ACC + 2] / ws[OFF_ACC + 3];
}

// ---------------- launch ----------------
extern "C" void kernel_launch(void* const* d_in, const int* in_sizes, int n_in,
                              void* d_out, int out_size, void* d_ws, size_t ws_size,
                              hipStream_t stream) {
  (void)in_sizes; (void)n_in; (void)ws_size;
  const int*   x       = (const int*)  d_in[0];
  const int*   labels  = (const int*)  d_in[1];
  const float* emb_enc = (const float*)d_in[3];
  const float* wih_f   = (const float*)d_in[4];
  const float* whh_f   = (const float*)d_in[5];
  const float* bih_f   = (const float*)d_in[6];
  const float* bhh_f   = (const float*)d_in[7];
  const float* wih_b   = (const float*)d_in[8];
  const float* whh_b   = (const float*)d_in[9];
  const float* bih_b   = (const float*)d_in[10];
  const float* bhh_b   = (const float*)d_in[11];
  const float* w_sel1  = (const float*)d_in[12];
  const float* b_sel1  = (const float*)d_in[13];
  const float* w_sel2  = (const float*)d_in[14];
  const float* b_sel2  = (const float*)d_in[15];
  const float* w_rh    = (const float*)d_in[16];
  const float* b_rh    = (const float*)d_in[17];
  const float* w_rc    = (const float*)d_in[18];
  const float* b_rc    = (const float*)d_in[19];
  const float* emb_dec = (const float*)d_in[20];
  const float* wih_d   = (const float*)d_in[21];
  const float* whh_d   = (const float*)d_in[22];
  const float* bih_d   = (const float*)d_in[23];
  const float* bhh_d   = (const float*)d_in[24];
  const float* w_attn  = (const float*)d_in[25];
  const float* b_attn  = (const float*)d_in[26];
  const float* w_attn_v= (const float*)d_in[27];
  const float* w_ptr   = (const float*)d_in[28];
  const float* b_ptr   = (const float*)d_in[29];
  const float* w_gen   = (const float*)d_in[30];
  const float* b_gen   = (const float*)d_in[31];
  const float* w_cov   = (const float*)d_in[32];
  const float* b_cov   = (const float*)d_in[33];
  float* ws  = (float*)d_ws;
  float* out = (float*)d_out;

  hipMemsetAsync(d_ws, 0, ZERO_FLOATS * 4, stream);
  k_biassum<<<12, 256, 0, stream>>>(bih_f, bhh_f, bih_b, bhh_b, bih_d, bhh_d, ws);
  k_embed<<<2000, 256, 0, stream>>>(x, labels, emb_enc, emb_dec, ws);
  k_gemm<64,64,4,4,0,0,0><<<dim3(25,16), 256, 0, stream>>>(ws+OFF_EMB,  wih_f, ws+OFF_BIAS,      ws+OFF_PREF, 1600, 256, 256, 1024);
  k_gemm<64,64,4,4,0,0,1><<<dim3(25,16), 256, 0, stream>>>(ws+OFF_EMB,  wih_b, ws+OFF_BIAS+1024, ws+OFF_PREB, 1600, 256, 256, 1024);
  k_gemm<64,64,4,4,0,0,0><<<dim3(7,16),  256, 0, stream>>>(ws+OFF_DEMB, wih_d, ws+OFF_BIAS+2048, ws+OFF_DPRE, 400,  256, 768, 1024);
  k_encoder<<<32, 512, 0, stream>>>(whh_f, whh_b, ws);
  k_gemm<64,64,4,4,0,1,0><<<dim3(25,4),  256, 0, stream>>>(ws+OFF_ENCOUT, w_sel1, b_sel1, ws+OFF_HSEL, 1600, 512, 512, 256);
  k_selbce<<<1600, 64, 0, stream>>>(w_sel2, b_sel2, x, ws);
  k_gemm<64,64,4,4,0,0,0><<<dim3(25,4),  256, 0, stream>>>(ws+OFF_ENCOUT, w_attn, b_attn, ws+OFF_EP, 1600, 512, 1024, 256);
  k_wcp<<<1, 256, 0, stream>>>(w_attn, w_cov, b_cov, ws);
  k_h0c0<<<8, 256, 0, stream>>>(w_rh, b_rh, w_rc, b_rc, ws);
  k_hw0<<<8, 256, 0, stream>>>(w_attn, ws);
  k_decoder<<<32, 512, 0, stream>>>(wih_d, whh_d, w_attn, w_attn_v, ws);
  k_pgen<<<400, 64, 0, stream>>>(w_ptr, b_ptr, ws);
  k_gemm<128,128,8,8,1,0,0><<<dim3(4,250), 256, 0, stream>>>(ws+OFF_HS, w_gen, b_gen, out, 400, 256, 256, 64000);
  k_v2<<<400, 256, 0, stream>>>(x, labels, ws, out);
  k_loss<<<1, 1, 0, stream>>>(ws, out, out_size);
}

// Round 4
// 2315.533 us; speedup vs baseline: 3.4879x; 1.1269x over previous
//
#include <hip/hip_runtime.h>
#include <hip/hip_bf16.h>
#include <stdint.h>

// B=8, S=200, H=256, V=32000, T=51. out = (8,50,64000) fp32 + scalar loss.

#define DEVI __device__ __forceinline__
#define AT_RLX __ATOMIC_RELAXED
#define SC_AGT __HIP_MEMORY_SCOPE_AGENT

// ---------------- ws layout (float offsets) ----------------
static constexpr size_t OFF_ACC   = 0;        // 4: nll_sum, valid_sum, bce_sum, m_sum
static constexpr size_t OFF_FLAGE = 4;        // 32 ints (encoder flags, 16/dir)
static constexpr size_t OFF_FLAGD = 36;       // 32 ints (decoder flags)
static constexpr size_t ZERO_FLOATS = 200;
static constexpr size_t OFF_CTX   = 256;      // 8*512 ctx accumulators
static constexpr size_t OFF_EMB   = 4352;     // [t][b][h] 200*8*256 (reused as HSEL)
static constexpr size_t OFF_HSEL  = OFF_EMB;
static constexpr size_t OFF_PREF  = OFF_EMB  + 409600;
static constexpr size_t OFF_PREB  = OFF_PREF + 1638400;
static constexpr size_t OFF_BIAS  = OFF_PREB + 1638400;  // 3072
static constexpr size_t OFF_HB    = OFF_BIAS + 3072;     // enc h dbl buf 8192
static constexpr size_t OFF_HFIN  = OFF_HB   + 8192;     // 4096
static constexpr size_t OFF_CFIN  = OFF_HFIN + 4096;     // 4096
static constexpr size_t OFF_ENCOUT= OFF_CFIN + 4096;     // [b][s][512] = 819200
static constexpr size_t OFF_MASK  = OFF_ENCOUT + 819200; // 1600
static constexpr size_t OFF_C0    = OFF_MASK + 1600;     // 2048
static constexpr size_t OFF_EP    = OFF_C0   + 2048;     // [b][s][256] = 409600
static constexpr size_t OFF_WCP   = OFF_EP   + 409600;   // 256
static constexpr size_t OFF_BCP   = OFF_WCP  + 256;      // 256
static constexpr size_t OFF_DEMB  = OFF_BCP  + 256;      // 102400
static constexpr size_t OFF_DPRE  = OFF_DEMB + 102400;   // 409600
static constexpr size_t OFF_HBUF  = OFF_DPRE + 409600;   // dec h dbl buf [2][2048]
static constexpr size_t OFF_CS    = OFF_HBUF + 4096;     // 204800
static constexpr size_t OFF_HS    = OFF_CS   + 204800;   // 102400
static constexpr size_t OFF_AS    = OFF_HS   + 102400;   // 80000
static constexpr size_t OFF_PG    = OFF_AS   + 80000;    // 400 (pad 512)
static constexpr size_t OFF_PE    = OFF_PG   + 512;      // pe [sq][b][200] = 6400

// ---------------- helpers ----------------
DEVI float sigf(float x)      { return 1.0f / (1.0f + __expf(-x)); }
DEVI float tanh_fast(float x) { return 1.0f - 2.0f / (1.0f + __expf(2.0f * x)); }
DEVI float pick4(float z, float x1, float x2, float x3, int mm) {
  return mm == 0 ? z : (mm == 1 ? x1 : (mm == 2 ? x2 : x3));
}
DEVI float ald(const float* p)  { return __hip_atomic_load((float*)p, AT_RLX, SC_AGT); }
DEVI void  ast(float* p, float v){ __hip_atomic_store(p, v, AT_RLX, SC_AGT); }

// Distributed flag barrier, RELAXED flag store (no L2 writeback needed:
// all cross-block data moves via agent-scope atomics that complete at the
// coherence point before __syncthreads' vmcnt(0) drain).
DEVI void fbar(int* flags, int g, int n, int val) {
  __syncthreads();
  if ((int)threadIdx.x == 0)
    __hip_atomic_store(flags + g, val, AT_RLX, SC_AGT);
  if ((int)threadIdx.x < n && (int)threadIdx.x != g) {
    while (__hip_atomic_load(flags + threadIdx.x, AT_RLX, SC_AGT) < val)
      __builtin_amdgcn_s_sleep(1);
  }
  __syncthreads();
}

// ---------------- small prep kernels ----------------
__global__ __launch_bounds__(256) void k_biassum(
    const float* bih_f, const float* bhh_f, const float* bih_b, const float* bhh_b,
    const float* bih_d, const float* bhh_d, float* ws) {
  int i = blockIdx.x * 256 + threadIdx.x;
  int which = i >> 10, jj = i & 1023;
  float v = (which == 0) ? bih_f[jj] + bhh_f[jj]
          : (which == 1) ? bih_b[jj] + bhh_b[jj]
                         : bih_d[jj] + bhh_d[jj];
  ws[OFF_BIAS + i] = v;
}

__global__ __launch_bounds__(256) void k_embed(
    const int* xin, const int* labels, const float* emb_enc, const float* emb_dec, float* ws) {
  int r = blockIdx.x, h = threadIdx.x;
  if (r < 1600) {
    int t = r >> 3, b = r & 7;
    ws[OFF_EMB + (size_t)r * 256 + h] = emb_enc[(size_t)xin[b * 200 + t] * 256 + h];
  } else {
    int r2 = r - 1600;
    int t = r2 >> 3, b = r2 & 7;
    int tok = (t == 0) ? 1 : labels[b * 51 + t];
    ws[OFF_DEMB + (size_t)r2 * 256 + h] = emb_dec[(size_t)tok * 256 + h];
  }
}

// ---------------- tiled SGEMM: C[m][n] = act(sum_k A[m][k]*B[n][k] + bias[n]) ----------------
template<int BM, int BN, int TM, int TN, int CMAP, int ACT, int AMAP>
__global__ __launch_bounds__(256) void k_gemm(
    const float* __restrict__ A, const float* __restrict__ B,
    const float* __restrict__ bias, float* __restrict__ C,
    int M, int K, int ldb, int ldc) {
  __shared__ float As[16][BM];
  __shared__ float Bs[16][BN];
  const int tid = threadIdx.x;
  const int tx = tid & 15, ty = tid >> 4;
  const int m0 = blockIdx.x * BM, n0 = blockIdx.y * BN;
  float acc[TM][TN];
#pragma unroll
  for (int i = 0; i < TM; ++i)
#pragma unroll
    for (int q = 0; q < TN; ++q) acc[i][q] = 0.f;

  for (int kk = 0; kk < K; kk += 16) {
#pragma unroll
    for (int e = tid; e < BM * 4; e += 256) {
      int m = e >> 2, k4 = (e & 3) * 4;
      int gm0 = m0 + m;
      float4 v = {0.f, 0.f, 0.f, 0.f};
      if (gm0 < M) {
        int gm = AMAP ? (((199 - (gm0 >> 3)) << 3) + (gm0 & 7)) : gm0;
        v = *(const float4*)(A + (size_t)gm * K + kk + k4);
      }
      As[k4 + 0][m] = v.x; As[k4 + 1][m] = v.y; As[k4 + 2][m] = v.z; As[k4 + 3][m] = v.w;
    }
#pragma unroll
    for (int e = tid; e < BN * 4; e += 256) {
      int n = e >> 2, k4 = (e & 3) * 4;
      float4 v = *(const float4*)(B + (size_t)(n0 + n) * ldb + kk + k4);
      Bs[k4 + 0][n] = v.x; Bs[k4 + 1][n] = v.y; Bs[k4 + 2][n] = v.z; Bs[k4 + 3][n] = v.w;
    }
    __syncthreads();
#pragma unroll
    for (int k = 0; k < 16; ++k) {
      float a[TM], bv[TN];
#pragma unroll
      for (int i = 0; i < TM; ++i) a[i] = As[k][ty * TM + i];
#pragma unroll
      for (int q = 0; q < TN; ++q) bv[q] = Bs[k][tx * TN + q];
#pragma unroll
      for (int i = 0; i < TM; ++i)
#pragma unroll
        for (int q = 0; q < TN; ++q) acc[i][q] += a[i] * bv[q];
    }
    __syncthreads();
  }
#pragma unroll
  for (int i = 0; i < TM; ++i) {
    int gm = m0 + ty * TM + i;
    if (gm >= M) continue;
    size_t base;
    if (CMAP == 1) { int t = gm >> 3, b = gm & 7; base = (size_t)(b * 50 + t) * 64000; }
    else            base = (size_t)gm * ldc;
#pragma unroll
    for (int q = 0; q < TN; ++q) {
      int n = n0 + tx * TN + q;
      float v = acc[i][q] + bias[n];
      if (ACT == 1) v = tanh_fast(v);
      C[base + n] = v;
    }
  }
}

// ---------------- encoder: 32 blocks (16/dir), weights in registers ----------------
__global__ __launch_bounds__(512, 1) void k_encoder(
    const float* __restrict__ whh_f, const float* __restrict__ whh_b, float* __restrict__ ws) {
  __shared__ float hs[8 * 288];
  __shared__ float zs[512];
  const int dir = blockIdx.x >> 4;
  const int p   = blockIdx.x & 15;
  const int u0  = p * 16;
  const float* whh = dir ? whh_b : whh_f;
  const float* pre = ws + (dir ? OFF_PREB : OFF_PREF);
  int* flags = (int*)(ws + OFF_FLAGE) + dir * 16;
  const int tid = threadIdx.x;
  const int r = tid >> 3, kc = tid & 7;
  const int gt = r >> 4, ui = r & 15;
  const int j = gt * 256 + u0 + ui;
  float4 W[8];
  {
    const float* wr = whh + (size_t)j * 256 + kc * 32;
#pragma unroll
    for (int q = 0; q < 8; ++q) W[q] = *(const float4*)(wr + q * 4);
  }
  const int ui2 = tid & 15, b2 = tid >> 4;
  float c_reg = 0.f;
  float* hBa = ws + OFF_HB;
  float* enc = ws + OFF_ENCOUT;

  for (int t = 0; t < 200; ++t) {
    float pre_v = pre[((size_t)t * 8 + kc) * 1024 + j];
    float acc[8];
#pragma unroll
    for (int b = 0; b < 8; ++b) acc[b] = 0.f;
    if (t > 0) {
      {
        float* src = hBa + (size_t)((((t + 1) & 1) * 2 + dir) * 2048) + tid * 4;
        float v0 = ald(src + 0);
        float v1 = ald(src + 1);
        float v2 = ald(src + 2);
        float v3 = ald(src + 3);
        int kk0 = (tid * 4) & 255, bb = tid >> 6;
        float* dst = &hs[bb * 288 + (kk0 >> 5) * 36 + (kk0 & 31)];
        dst[0] = v0; dst[1] = v1; dst[2] = v2; dst[3] = v3;
      }
      __syncthreads();
      const float* hrow = &hs[kc * 36];
#pragma unroll
      for (int b = 0; b < 8; ++b) {
        const float* hbp = hrow + b * 288;
#pragma unroll
        for (int q = 0; q < 8; ++q) {
          float4 h4 = *(const float4*)(hbp + q * 4);
          acc[b] = fmaf(W[q].x, h4.x, acc[b]);
          acc[b] = fmaf(W[q].y, h4.y, acc[b]);
          acc[b] = fmaf(W[q].z, h4.z, acc[b]);
          acc[b] = fmaf(W[q].w, h4.w, acc[b]);
        }
      }
    }
    {
      bool h4b = (kc & 4) != 0;
#pragma unroll
      for (int i = 0; i < 4; ++i) {
        float send = h4b ? acc[i] : acc[i + 4];
        float keep = h4b ? acc[i + 4] : acc[i];
        acc[i] = keep + __shfl_xor(send, 4);
      }
      bool h2b = (kc & 2) != 0;
#pragma unroll
      for (int i = 0; i < 2; ++i) {
        float send = h2b ? acc[i] : acc[i + 2];
        float keep = h2b ? acc[i + 2] : acc[i];
        acc[i] = keep + __shfl_xor(send, 2);
      }
      bool h1b = (kc & 1) != 0;
      {
        float send = h1b ? acc[0] : acc[1];
        float keep = h1b ? acc[1] : acc[0];
        acc[0] = keep + __shfl_xor(send, 1);
      }
    }
    zs[tid] = acc[0] + pre_v;
    __syncthreads();
    if (tid < 128) {
      int i0 = ui2 * 8 + b2;
      float zi = zs[i0], zf = zs[128 + i0], zg = zs[256 + i0], zo = zs[384 + i0];
      float cn = sigf(zf) * c_reg + sigf(zi) * tanh_fast(zg);
      float hn = sigf(zo) * tanh_fast(cn);
      c_reg = cn;
      int uu = u0 + ui2;
      ast(hBa + (size_t)(((t & 1) * 2 + dir) * 2048) + b2 * 256 + uu, hn);
      int s = dir ? (199 - t) : t;
      enc[((size_t)b2 * 200 + s) * 512 + dir * 256 + uu] = hn;
      if (t == 199) {
        ws[OFF_HFIN + (size_t)(dir * 8 + b2) * 256 + uu] = hn;
        ws[OFF_CFIN + (size_t)(dir * 8 + b2) * 256 + uu] = cn;
      }
    }
    if (t < 199) fbar(flags, p, 16, t + 1);
  }
}

// ---------------- copy-prob head + BCE ----------------
__global__ __launch_bounds__(64) void k_selbce(
    const float* w_sel2, const float* b_sel2, const int* xin, float* ws) {
  int r = blockIdx.x, lane = threadIdx.x;
  float pacc = 0.f;
#pragma unroll
  for (int i = 0; i < 4; ++i) {
    int k = lane + 64 * i;
    pacc += ws[OFF_HSEL + (size_t)r * 256 + k] * w_sel2[k];
  }
#pragma unroll
  for (int m = 1; m < 64; m <<= 1) pacc += __shfl_xor(pacc, m);
  if (lane == 0) {
    float cp = sigf(pacc + b_sel2[0]);
    ws[OFF_MASK + r] = (cp > 1e-8f) ? 1.f : 0.f;
    int b = r / 200, s = r % 200;
    float m = (xin[b * 200 + s] != 0) ? 1.f : 0.f;
    if (m > 0.f) {
      float lp = fmaxf(logf(cp), -100.f);
      atomicAdd(ws + OFF_ACC + 2, -lp);
    }
    atomicAdd(ws + OFF_ACC + 3, m);
  }
}

__global__ __launch_bounds__(256) void k_wcp(
    const float* w_attn, const float* w_cov, const float* b_cov, float* ws) {
  int jj = threadIdx.x;
  float a = 0.f, c = 0.f;
  for (int h = 0; h < 256; ++h) {
    float w = w_attn[(size_t)jj * 1024 + 768 + h];
    a += w * w_cov[h];
    c += w * b_cov[h];
  }
  ws[OFF_WCP + jj] = a;
  ws[OFF_BCP + jj] = c;
}

__global__ __launch_bounds__(256) void k_h0c0(
    const float* w_rh, const float* b_rh, const float* w_rc, const float* b_rc, float* ws) {
  int b = blockIdx.x, jj = threadIdx.x;
  const float* hf  = ws + OFF_HFIN + (size_t)b * 256;
  const float* hbk = ws + OFF_HFIN + 2048 + (size_t)b * 256;
  const float* cf  = ws + OFF_CFIN + (size_t)b * 256;
  const float* cbk = ws + OFF_CFIN + 2048 + (size_t)b * 256;
  float ah = b_rh[jj], ac = b_rc[jj];
  for (int k = 0; k < 256; ++k) {
    ah += hf[k] * w_rh[(size_t)jj * 512 + k];
    ac += cf[k] * w_rc[(size_t)jj * 512 + k];
  }
  for (int k = 0; k < 256; ++k) {
    ah += hbk[k] * w_rh[(size_t)jj * 512 + 256 + k];
    ac += cbk[k] * w_rc[(size_t)jj * 512 + 256 + k];
  }
  ws[OFF_C0 + (size_t)b * 256 + jj] = fmaxf(ac, 0.f);
  ws[OFF_HBUF + (size_t)b * 256 + jj] = fmaxf(ah, 0.f);   // dec h buf0
}

// ---------------- decoder: 32 blocks, jj-separable attention, h-only exchange ----------------
__global__ __launch_bounds__(512, 1) void k_decoder(
    const float* __restrict__ wih_d, const float* __restrict__ whh_d,
    const float* __restrict__ w_attn, const float* __restrict__ w_attn_v,
    float* __restrict__ ws) {
  __shared__ float hc_s[8 * 768];     // [b][ctx512 | h256]
  __shared__ float h_pad[264];        // h[b1] staged, 32->33-pad chunks (36 stride)
  __shared__ float hw_q[64];          // hW quarter
  __shared__ float e_s[256];
  __shared__ float at_s[256], cv_s[256], msk_s[256];
  __shared__ float zs_l[256];
  __shared__ float wcq_s[64], bcq_s[64], wvq_s[64];
  __shared__ float mS_s[2];
  const int g = blockIdx.x, tid = threadIdx.x;
  const int b1 = g >> 2, sq = g & 3, s0 = sq * 50;
  int* flags = (int*)(ws + OFF_FLAGD);
  // hw role: jl = tid>>3 (jj within quarter), kq = tid&7 (k-chunk of 32)
  const int jl = tid >> 3, kq = tid & 7;
  // LSTM role (R3-proven): kseg in [0,16), row_l in [0,32)
  const int kseg = tid & 15, row_l = tid >> 4;
  const int u_l = row_l & 7, gate = row_l >> 3;
  const int j = gate * 256 + g * 8 + u_l;
  float4 W48[12];
#pragma unroll
  for (int q = 0; q < 12; ++q) {
    int k0 = 4 * kseg + 64 * q;
    W48[q] = (k0 < 512) ? *(const float4*)(wih_d + (size_t)j * 768 + 256 + k0)
                        : *(const float4*)(whh_d + (size_t)j * 256 + (k0 - 512));
  }
  // waT quarter: W32[q] = w_attn[sq*64+jl][512 + kq*32 + q*4 ..]
  float4 W32[8];
  {
    const float* wsrc = w_attn + (size_t)(sq * 64 + jl) * 1024 + 512 + kq * 32;
#pragma unroll
    for (int q = 0; q < 8; ++q) W32[q] = *(const float4*)(wsrc + q * 4);
  }
  // cell role: tid<64
  const int u_c = tid & 7, b_c = tid >> 3;
  float c_reg = (tid < 64) ? ws[OFF_C0 + (size_t)b_c * 256 + g * 8 + u_c] : 0.f;
  for (int s = tid; s < 256; s += 512) {
    msk_s[s] = (s < 200) ? ws[OFF_MASK + b1 * 200 + s] : 0.f;
    cv_s[s] = 0.f;
  }
  if (tid < 64) {
    wcq_s[tid] = ws[OFF_WCP + sq * 64 + tid];
    bcq_s[tid] = ws[OFF_BCP + sq * 64 + tid];
    wvq_s[tid] = w_attn_v[sq * 64 + tid];
  }
  __syncthreads();

  for (int t = 0; t < 50; ++t) {
    const int rb = t & 1, wb = 1 - rb;
    // ---- Phase B: zero ctx slice; stage h[b1]; hW quarter; partial scores pe ----
    if (tid < 128) ast(ws + OFF_CTX + g * 128 + tid, 0.f);
    if (tid < 256) {
      float v = ald(ws + OFF_HBUF + (size_t)rb * 2048 + b1 * 256 + tid);
      h_pad[(tid >> 5) * 33 + (tid & 31)] = v;
    }
    __syncthreads();
    {
      float a = 0.f;
      const float* hp = &h_pad[kq * 33 * 4 / 4];   // kq*32 floats -> padded base kq*33... use chunked:
      // h_pad chunk c (32 floats) starts at c*33; our 32-float window is exactly chunk kq? kq*32 aligned: yes.
      const float* hq = &h_pad[kq * 33];
#pragma unroll
      for (int q = 0; q < 8; ++q) {
        float4 h4 = { hq[q * 4 + 0], hq[q * 4 + 1], hq[q * 4 + 2], hq[q * 4 + 3] };
        a = fmaf(W32[q].x, h4.x, a);
        a = fmaf(W32[q].y, h4.y, a);
        a = fmaf(W32[q].z, h4.z, a);
        a = fmaf(W32[q].w, h4.w, a);
      }
      (void)hp;
      a += __shfl_xor(a, 1);
      a += __shfl_xor(a, 2);
      a += __shfl_xor(a, 4);
      if (kq == 0) hw_q[jl] = a;
    }
    __syncthreads();
    if (tid < 200) {
      const int s = tid;
      float cv = cv_s[s];
      const float* ep = ws + OFF_EP + ((size_t)(b1 * 200 + s)) * 256 + sq * 64;
      float pe = 0.f;
#pragma unroll
      for (int i4 = 0; i4 < 16; ++i4) {
        float4 e4 = *(const float4*)(ep + i4 * 4);
        float4 h4 = *(const float4*)(&hw_q[i4 * 4]);
        float4 w4 = *(const float4*)(&wcq_s[i4 * 4]);
        float4 b4 = *(const float4*)(&bcq_s[i4 * 4]);
        float4 v4 = *(const float4*)(&wvq_s[i4 * 4]);
        pe = fmaf(tanh_fast(e4.x + h4.x + cv * w4.x + b4.x), v4.x, pe);
        pe = fmaf(tanh_fast(e4.y + h4.y + cv * w4.y + b4.y), v4.y, pe);
        pe = fmaf(tanh_fast(e4.z + h4.z + cv * w4.z + b4.z), v4.z, pe);
        pe = fmaf(tanh_fast(e4.w + h4.w + cv * w4.w + b4.w), v4.w, pe);
      }
      ast(ws + OFF_PE + (size_t)(sq * 8 + b1) * 200 + s, pe);
    }
    fbar(flags, g, 32, 3 * t + 1);

    // ---- Phase C: full scores, softmax (local, deterministic), attn, cov, ctx partial ----
    if (tid < 200) {
      float e0 = ald(ws + OFF_PE + (size_t)(0 * 8 + b1) * 200 + tid);
      float e1 = ald(ws + OFF_PE + (size_t)(1 * 8 + b1) * 200 + tid);
      float e2 = ald(ws + OFF_PE + (size_t)(2 * 8 + b1) * 200 + tid);
      float e3 = ald(ws + OFF_PE + (size_t)(3 * 8 + b1) * 200 + tid);
      e_s[tid] = (e0 + e1) + (e2 + e3);
    }
    __syncthreads();
    if (tid < 64) {
      float m = -1e30f;
#pragma unroll
      for (int i = 0; i < 4; ++i) {
        int s = tid + 64 * i;
        if (s < 200) m = fmaxf(m, e_s[s]);
      }
#pragma unroll
      for (int md = 1; md < 64; md <<= 1) m = fmaxf(m, __shfl_xor(m, md));
      float es = 0.f, ems = 0.f;
#pragma unroll
      for (int i = 0; i < 4; ++i) {
        int s = tid + 64 * i;
        if (s < 200) {
          float e = __expf(e_s[s] - m);
          es += e; ems += e * msk_s[s];
        }
      }
#pragma unroll
      for (int md = 1; md < 64; md <<= 1) { es += __shfl_xor(es, md); ems += __shfl_xor(ems, md); }
      if (tid == 0) { mS_s[0] = m; mS_s[1] = 1.0f / (ems + 1e-10f * es); }
    }
    __syncthreads();
    if (tid < 200) {
      float a = __expf(e_s[tid] - mS_s[0]) * msk_s[tid] * mS_s[1];
      at_s[tid] = a;
      cv_s[tid] += a;
      if (tid >= s0 && tid < s0 + 50)
        ws[OFF_AS + ((size_t)t * 8 + b1) * 200 + tid] = a;
    }
    __syncthreads();
    {
      float ca = 0.f;
      const float* ebase = ws + OFF_ENCOUT + ((size_t)(b1 * 200 + s0)) * 512 + tid;
#pragma unroll 10
      for (int s2 = 0; s2 < 50; ++s2)
        ca = fmaf(at_s[s0 + s2], ebase[(size_t)s2 * 512], ca);
      atomicAdd(ws + OFF_CTX + b1 * 512 + tid, ca);
    }
    fbar(flags, g, 32, 3 * t + 2);

    // ---- LSTM phase: stage hcat, gates (reg weights), cell, publish h ----
    for (int e = tid; e < 6144; e += 512) {
      int bb = e / 768, kk2 = e % 768;
      hc_s[e] = (kk2 < 512) ? ald(ws + OFF_CTX + bb * 512 + kk2)
                            : ald(ws + OFF_HBUF + (size_t)rb * 2048 + bb * 256 + (kk2 - 512));
    }
    __syncthreads();
    if (g < 8) ws[OFF_CS + ((size_t)t * 8 + g) * 512 + tid] = hc_s[g * 768 + tid];
    float acc[8];
#pragma unroll
    for (int b = 0; b < 8; ++b) acc[b] = 0.f;
#pragma unroll
    for (int q = 0; q < 12; ++q) {
      int k0 = 4 * kseg + 64 * q;
#pragma unroll
      for (int b = 0; b < 8; ++b) {
        float4 h4 = *(const float4*)(&hc_s[b * 768 + k0]);
        acc[b] = fmaf(W48[q].x, h4.x, acc[b]);
        acc[b] = fmaf(W48[q].y, h4.y, acc[b]);
        acc[b] = fmaf(W48[q].z, h4.z, acc[b]);
        acc[b] = fmaf(W48[q].w, h4.w, acc[b]);
      }
    }
    {
      bool h8 = (kseg & 8) != 0;
#pragma unroll
      for (int i = 0; i < 4; ++i) {
        float send = h8 ? acc[i] : acc[i + 4];
        float keep = h8 ? acc[i + 4] : acc[i];
        acc[i] = keep + __shfl_xor(send, 8);
      }
      bool h4b = (kseg & 4) != 0;
#pragma unroll
      for (int i = 0; i < 2; ++i) {
        float send = h4b ? acc[i] : acc[i + 2];
        float keep = h4b ? acc[i + 2] : acc[i];
        acc[i] = keep + __shfl_xor(send, 4);
      }
      bool h2b = (kseg & 2) != 0;
      {
        float send = h2b ? acc[0] : acc[1];
        float keep = h2b ? acc[1] : acc[0];
        acc[0] = keep + __shfl_xor(send, 2);
      }
      acc[0] += __shfl_xor(acc[0], 1);
    }
    {
      int bz = kseg >> 1;
      float z = acc[0] + ws[OFF_DPRE + ((size_t)t * 8 + bz) * 1024 + j];
      if ((kseg & 1) == 0) zs_l[row_l * 8 + bz] = z;
    }
    __syncthreads();
    if (tid < 64) {
      float zi = zs_l[(0  + u_c) * 8 + b_c];
      float zf = zs_l[(8  + u_c) * 8 + b_c];
      float zg = zs_l[(16 + u_c) * 8 + b_c];
      float zo = zs_l[(24 + u_c) * 8 + b_c];
      float cn = sigf(zf) * c_reg + sigf(zi) * tanh_fast(zg);
      float hn = sigf(zo) * tanh_fast(cn);
      c_reg = cn;
      ast(ws + OFF_HBUF + (size_t)wb * 2048 + b_c * 256 + g * 8 + u_c, hn);
      ws[OFF_HS + ((size_t)t * 8 + b_c) * 256 + g * 8 + u_c] = hn;
    }
    fbar(flags, g, 32, 3 * t + 3);
  }
}

__global__ __launch_bounds__(64) void k_pgen(const float* w_ptr, const float* b_ptr, float* ws) {
  int r = blockIdx.x, lane = threadIdx.x;
  float p = 0.f;
#pragma unroll
  for (int i = 0; i < 12; ++i) {
    int k = lane + 64 * i;
    float v = (k < 512) ? ws[OFF_CS + (size_t)r * 512 + k]
                        : ws[OFF_HS + (size_t)r * 256 + (k - 512)];
    p += v * w_ptr[k];
  }
#pragma unroll
  for (int m = 1; m < 64; m <<= 1) p += __shfl_xor(p, m);
  if (lane == 0) ws[OFF_PG + r] = sigf(p + b_ptr[0]);
}

// ---------------- fused vocab softmax + pointer scatter + CE loss ----------------
__global__ __launch_bounds__(256) void k_v2(const int* xin, const int* labels, float* ws, float* out) {
  __shared__ float redm[256], reds[256];
  __shared__ int xv[200];
  __shared__ float s1sh, corrsh;
  int r = blockIdx.x, tid = threadIdx.x;
  int tt = r >> 3, b = r & 7;
  float* row = out + (size_t)(b * 50 + tt) * 64000;
  for (int i = tid; i < 200; i += 256) xv[i] = xin[b * 200 + i];
  float m = -1e30f, s = 0.f;
  for (int i = tid; i < 32000; i += 256) {
    float z = row[i];
    float nm = fmaxf(m, z);
    s = s * __expf(m - nm) + __expf(z - nm);
    m = nm;
  }
  redm[tid] = m; reds[tid] = s;
  __syncthreads();
  for (int st = 128; st >= 1; st >>= 1) {
    if (tid < st) {
      float m2 = redm[tid + st], s2 = reds[tid + st];
      float M = fmaxf(redm[tid], m2);
      reds[tid] = reds[tid] * __expf(redm[tid] - M) + s2 * __expf(m2 - M);
      redm[tid] = M;
    }
    __syncthreads();
  }
  float mx = redm[0], sum = reds[0];
  float pg = ws[OFF_PG + r];
  __syncthreads();
  float s1 = 0.f;
  float inv = 1.0f / sum;
  for (int i = tid; i < 32000; i += 256) {
    float z = row[i];
    float d = pg * (__expf(z - mx) * inv);
    row[i] = d;
    s1 += __expf(d);
  }
  for (int i = 32000 + tid; i < 64000; i += 256) row[i] = 0.0f;
  reds[tid] = s1;
  __syncthreads();
  for (int st = 128; st >= 1; st >>= 1) { if (tid < st) reds[tid] += reds[tid + st]; __syncthreads(); }
  if (tid == 0) { s1sh = reds[0]; corrsh = 0.f; }
  __syncthreads();
  if (tid < 200) {
    int v = xv[tid];
    bool own = true;
    for (int s2 = 0; s2 < tid; ++s2) if (xv[s2] == v) { own = false; break; }
    if (own) {
      float delta = 0.f;
      for (int s2 = tid; s2 < 200; ++s2)
        if (xv[s2] == v) delta += ws[OFF_AS + (size_t)r * 200 + s2];
      delta *= (1.0f - pg);
      float base = row[v];
      row[v] = base + delta;
      atomicAdd(&corrsh, __expf(base + delta) - __expf(base));
    }
  }
  __syncthreads();
  if (tid == 0) {
    float lse = logf(s1sh + corrsh + 32000.0f);
    int tgt = labels[b * 51 + tt + 1];
    float dt = row[tgt];
    float valid = (tgt != 0) ? 1.f : 0.f;
    atomicAdd(ws + OFF_ACC + 0, valid * (lse - dt));
    atomicAdd(ws + OFF_ACC + 1, valid);
  }
}

__global__ void k_loss(float* ws, float* out, int out_size) {
  out[out_size - 1] = ws[OFF_ACC + 0] / ws[OFF_ACC + 1] + ws[OFF_ACC + 2] / ws[OFF_ACC + 3];
}

// ---------------- launch ----------------
extern "C" void kernel_launch(void* const* d_in, const int* in_sizes, int n_in,
                              void* d_out, int out_size, void* d_ws, size_t ws_size,
                              hipStream_t stream) {
  (void)in_sizes; (void)n_in; (void)ws_size;
  const int*   x       = (const int*)  d_in[0];
  const int*   labels  = (const int*)  d_in[1];
  const float* emb_enc = (const float*)d_in[3];
  const float* wih_f   = (const float*)d_in[4];
  const float* whh_f   = (const float*)d_in[5];
  const float* bih_f   = (const float*)d_in[6];
  const float* bhh_f   = (const float*)d_in[7];
  const float* wih_b   = (const float*)d_in[8];
  const float* whh_b   = (const float*)d_in[9];
  const float* bih_b   = (const float*)d_in[10];
  const float* bhh_b   = (const float*)d_in[11];
  const float* w_sel1  = (const float*)d_in[12];
  const float* b_sel1  = (const float*)d_in[13];
  const float* w_sel2  = (const float*)d_in[14];
  const float* b_sel2  = (const float*)d_in[15];
  const float* w_rh    = (const float*)d_in[16];
  const float* b_rh    = (const float*)d_in[17];
  const float* w_rc    = (const float*)d_in[18];
  const float* b_rc    = (const float*)d_in[19];
  const float* emb_dec = (const float*)d_in[20];
  const float* wih_d   = (const float*)d_in[21];
  const float* whh_d   = (const float*)d_in[22];
  const float* bih_d   = (const float*)d_in[23];
  const float* bhh_d   = (const float*)d_in[24];
  const float* w_attn  = (const float*)d_in[25];
  const float* b_attn  = (const float*)d_in[26];
  const float* w_attn_v= (const float*)d_in[27];
  const float* w_ptr   = (const float*)d_in[28];
  const float* b_ptr   = (const float*)d_in[29];
  const float* w_gen   = (const float*)d_in[30];
  const float* b_gen   = (const float*)d_in[31];
  const float* w_cov   = (const float*)d_in[32];
  const float* b_cov   = (const float*)d_in[33];
  float* ws  = (float*)d_ws;
  float* out = (float*)d_out;

  hipMemsetAsync(d_ws, 0, ZERO_FLOATS * 4, stream);
  k_biassum<<<12, 256, 0, stream>>>(bih_f, bhh_f, bih_b, bhh_b, bih_d, bhh_d, ws);
  k_embed<<<2000, 256, 0, stream>>>(x, labels, emb_enc, emb_dec, ws);
  k_gemm<64,64,4,4,0,0,0><<<dim3(25,16), 256, 0, stream>>>(ws+OFF_EMB,  wih_f, ws+OFF_BIAS,      ws+OFF_PREF, 1600, 256, 256, 1024);
  k_gemm<64,64,4,4,0,0,1><<<dim3(25,16), 256, 0, stream>>>(ws+OFF_EMB,  wih_b, ws+OFF_BIAS+1024, ws+OFF_PREB, 1600, 256, 256, 1024);
  k_gemm<64,64,4,4,0,0,0><<<dim3(7,16),  256, 0, stream>>>(ws+OFF_DEMB, wih_d, ws+OFF_BIAS+2048, ws+OFF_DPRE, 400,  256, 768, 1024);
  k_encoder<<<32, 512, 0, stream>>>(whh_f, whh_b, ws);
  k_gemm<64,64,4,4,0,1,0><<<dim3(25,4),  256, 0, stream>>>(ws+OFF_ENCOUT, w_sel1, b_sel1, ws+OFF_HSEL, 1600, 512, 512, 256);
  k_selbce<<<1600, 64, 0, stream>>>(w_sel2, b_sel2, x, ws);
  k_gemm<64,64,4,4,0,0,0><<<dim3(25,4),  256, 0, stream>>>(ws+OFF_ENCOUT, w_attn, b_attn, ws+OFF_EP, 1600, 512, 1024, 256);
  k_wcp<<<1, 256, 0, stream>>>(w_attn, w_cov, b_cov, ws);
  k_h0c0<<<8, 256, 0, stream>>>(w_rh, b_rh, w_rc, b_rc, ws);
  k_decoder<<<32, 512, 0, stream>>>(wih_d, whh_d, w_attn, w_attn_v, ws);
  k_pgen<<<400, 64, 0, stream>>>(w_ptr, b_ptr, ws);
  k_gemm<128,128,8,8,1,0,0><<<dim3(4,250), 256, 0, stream>>>(ws+OFF_HS, w_gen, b_gen, out, 400, 256, 256, 64000);
  k_v2<<<400, 256, 0, stream>>>(x, labels, ws, out);
  k_loss<<<1, 1, 0, stream>>>(ws, out, out_size);
}